// Round 10
// baseline (198.805 us; speedup 1.0000x reference)
//
#include <hip/hip_runtime.h>
#include <hip/hip_cooperative_groups.h>

namespace cg = cooperative_groups;

#define T_ 1024
#define B_ 4
#define E_ 512
#define H_ 8
#define D_ 64
#define P_ 64
#define K2 128            // 2P
#define N_ (T_*B_)        // 4096 rows (t*B + b)
#define CHK 64            // scan chunk length
#define NC (T_/CHK)       // 16 chunks
#define BH (B_*H_)        // 32
#define EPSV 1e-6f

typedef unsigned int uint;
typedef unsigned short ushort;
typedef short short8 __attribute__((ext_vector_type(8)));   // 8 bf16 (MFMA A/B frag)
typedef float f32x4 __attribute__((ext_vector_type(4)));    // MFMA C/D frag

__device__ __forceinline__ float b2f(ushort u){ return __uint_as_float(((uint)u) << 16); }
__device__ __forceinline__ ushort f2b(float f){
  uint x = __float_as_uint(f);
  return (ushort)((x + 0x7fffu + ((x >> 16) & 1u)) >> 16);   // RNE
}
__device__ __forceinline__ float lo16(uint u){ return __uint_as_float(u << 16); }
__device__ __forceinline__ float hi16(uint u){ return __uint_as_float(u & 0xffff0000u); }
__device__ __forceinline__ void st(float* p, float v){ *p = v; }
__device__ __forceinline__ void st(ushort* p, float v){ *p = f2b(v); }

// async global->LDS, 16B per lane; LDS dest = wave-uniform base + lane*16 (m104)
__device__ __forceinline__ void gl16(const ushort* g, ushort* lds) {
  __builtin_amdgcn_global_load_lds(
      (const __attribute__((address_space(1))) uint*)g,
      (__attribute__((address_space(3))) uint*)lds, 16, 0, 0);
}

// ---------------- cast f32 -> bf16 (x + 4 weights + rm) ----------------
__global__ __launch_bounds__(256) void cast_kernel(
    const float* __restrict__ x, const float* __restrict__ wq, const float* __restrict__ wk,
    const float* __restrict__ wv, const float* __restrict__ wo, const float* __restrict__ rm,
    ushort* __restrict__ xb, ushort* __restrict__ wqb, ushort* __restrict__ wkb,
    ushort* __restrict__ wvb, ushort* __restrict__ wob, ushort* __restrict__ rmb)
{
  const float* src; ushort* dst; int n4;
  switch (blockIdx.y) {
    case 0:  src = x;  dst = xb;  n4 = N_ * E_ / 4; break;
    case 1:  src = wq; dst = wqb; n4 = E_ * E_ / 4; break;
    case 2:  src = wk; dst = wkb; n4 = E_ * E_ / 4; break;
    case 3:  src = wv; dst = wvb; n4 = E_ * E_ / 4; break;
    case 4:  src = wo; dst = wob; n4 = E_ * E_ / 4; break;
    default: src = rm; dst = rmb; n4 = H_ * P_ * D_ / 4; break;
  }
  const int stride = gridDim.x * 256;
  for (int i = blockIdx.x * 256 + threadIdx.x; i < n4; i += stride) {
    const float4 v = *(const float4*)(src + (size_t)i * 4);
    ushort4 o; o.x = f2b(v.x); o.y = f2b(v.y); o.z = f2b(v.z); o.w = f2b(v.w);
    *(ushort4*)(dst + (size_t)i * 4) = o;
  }
}

// ---------------- LDS-staged MFMA GEMM tile: 128x64, BK=32, 2 waves ----------------
template<typename OutT>
__device__ __forceinline__ void gemm_tile(
    const ushort* __restrict__ A, const ushort* __restrict__ W,
    const float* __restrict__ bias, OutT* __restrict__ out,
    const int row0, const int col0)
{
  __shared__ ushort sA[128 * 32];   // [row][k] rows of 64B, linear
  __shared__ ushort sB[64 * 32];
  const int tid = threadIdx.x, w = tid >> 6, lane = tid & 63;
  const int lrow = lane >> 2, lk8 = (lane & 3) * 8;
  const ushort* gA = A + (size_t)(row0 + w * 16 + lrow) * E_ + lk8;
  const ushort* gB = W + (size_t)(col0 + w * 16 + lrow) * E_ + lk8;
  ushort* lA = sA + w * 512;
  ushort* lB = sB + w * 512;
  const int r = lane & 15, kg = lane >> 4, kq = kg * 8;
  f32x4 acc[4][4] = {};
  for (int k0 = 0; k0 < E_; k0 += 32) {
    gl16(gA + k0,             lA);
    gl16(gA + k0 + 32 * E_,   lA + 1024);
    gl16(gA + k0 + 64 * E_,   lA + 2048);
    gl16(gA + k0 + 96 * E_,   lA + 3072);
    gl16(gB + k0,             lB);
    gl16(gB + k0 + 32 * E_,   lB + 1024);
    __syncthreads();
    short8 af[4], bf[4];
    #pragma unroll
    for (int m = 0; m < 4; ++m) af[m] = *(const short8*)(sA + (w * 64 + m * 16 + r) * 32 + kq);
    #pragma unroll
    for (int n = 0; n < 4; ++n) bf[n] = *(const short8*)(sB + (n * 16 + r) * 32 + kq);
    #pragma unroll
    for (int m = 0; m < 4; ++m)
      #pragma unroll
      for (int n = 0; n < 4; ++n)
        acc[m][n] = __builtin_amdgcn_mfma_f32_16x16x32_bf16(af[m], bf[n], acc[m][n], 0, 0, 0);
    __syncthreads();
  }
  float bs[4];
  #pragma unroll
  for (int n = 0; n < 4; ++n) bs[n] = bias[col0 + n * 16 + r];
  #pragma unroll
  for (int m = 0; m < 4; ++m) {
    #pragma unroll
    for (int j = 0; j < 4; ++j) {
      const int row_g = row0 + w * 64 + m * 16 + kg * 4 + j;
      #pragma unroll
      for (int n = 0; n < 4; ++n)
        st(out + (size_t)row_g * E_ + col0 + n * 16 + r, acc[m][n][j] + bs[n]);
    }
  }
}

__global__ __launch_bounds__(128) void gemm_qkv_kernel(
    const ushort* __restrict__ A,
    const ushort* __restrict__ wq, const ushort* __restrict__ wk, const ushort* __restrict__ wv,
    const float* __restrict__ bq, const float* __restrict__ bk, const float* __restrict__ bv,
    ushort* __restrict__ qb, ushort* __restrict__ kb, ushort* __restrict__ vb)
{
  const ushort* W; const float* bias; ushort* dst;
  if (blockIdx.z == 0)      { W = wq; bias = bq; dst = qb; }
  else if (blockIdx.z == 1) { W = wk; bias = bk; dst = kb; }
  else                      { W = wv; bias = bv; dst = vb; }
  gemm_tile<ushort>(A, W, bias, dst, blockIdx.x * 128, blockIdx.y * 64);
}

__global__ __launch_bounds__(128) void gemm_out_kernel(
    const ushort* __restrict__ A, const ushort* __restrict__ W,
    const float* __restrict__ bias, float* __restrict__ out)
{
  gemm_tile<float>(A, W, bias, out, blockIdx.x * 128, blockIdx.y * 64);
}

// ---------------- phi via MFMA (round-6 version, separate dispatch) ----------------
__global__ __launch_bounds__(256) void phi_kernel(
    const ushort* __restrict__ qb, const ushort* __restrict__ kb,
    const ushort* __restrict__ rmb, ushort* __restrict__ pq, ushort* __restrict__ pk)
{
  __shared__ ushort xq[64][72];    // q tile [n][d]
  __shared__ ushort rms[64][72];   // rm[h]  [p][d]
  __shared__ float inv_s[64];
  const int tid = threadIdx.x;
  const int h = blockIdx.y;
  const ushort* src = blockIdx.z ? kb : qb;
  ushort* dst = blockIdx.z ? pk : pq;
  const int n0 = blockIdx.x * 64;
  const int row = tid >> 2, seg = (tid & 3) * 16;
  {
    const ushort* gq = src + (size_t)(n0 + row) * E_ + h * D_ + seg;
    const ushort* gr = rmb + ((size_t)h * P_ + row) * D_ + seg;
    const uint4 q0 = *(const uint4*)(gq);
    const uint4 q1 = *(const uint4*)(gq + 8);
    *(uint4*)(&xq[row][seg])      = q0;
    *(uint4*)(&xq[row][seg + 8])  = q1;
    *(uint4*)(&rms[row][seg])     = *(const uint4*)(gr);
    *(uint4*)(&rms[row][seg + 8]) = *(const uint4*)(gr + 8);
    float s2 = 0.f;
    const uint* qw = (const uint*)&q0;
    #pragma unroll
    for (int i = 0; i < 4; ++i) { const float a = lo16(qw[i]), b = hi16(qw[i]); s2 += a*a + b*b; }
    const uint* qw1 = (const uint*)&q1;
    #pragma unroll
    for (int i = 0; i < 4; ++i) { const float a = lo16(qw1[i]), b = hi16(qw1[i]); s2 += a*a + b*b; }
    s2 += __shfl_xor(s2, 1, 64);
    s2 += __shfl_xor(s2, 2, 64);
    if ((tid & 3) == 0) inv_s[row] = 1.0f / fmaxf(sqrtf(s2), EPSV);
  }
  __syncthreads();
  const int w = tid >> 6, lane = tid & 63;
  const int r = lane & 15, kg = lane >> 4;
  const int m0 = w * 16;
  f32x4 acc[4] = {};
  #pragma unroll
  for (int k0 = 0; k0 < D_; k0 += 32) {
    const short8 a = *(const short8*)(&xq[m0 + r][k0 + kg * 8]);
    #pragma unroll
    for (int nt = 0; nt < 4; ++nt) {
      const short8 bfr = *(const short8*)(&rms[nt * 16 + r][k0 + kg * 8]);
      acc[nt] = __builtin_amdgcn_mfma_f32_16x16x32_bf16(a, bfr, acc[nt], 0, 0, 0);
    }
  }
  #pragma unroll
  for (int j = 0; j < 4; ++j) {
    const int rr = m0 + kg * 4 + j;
    const float inv = inv_s[rr];
    const size_t base = ((size_t)(n0 + rr) * H_ + h) * K2;
    #pragma unroll
    for (int nt = 0; nt < 4; ++nt) {
      const int p = nt * 16 + r;
      const float proj = acc[nt][j] * inv;
      dst[base + p]      = f2b(__sinf(proj) * 0.125f);   // P^-0.5
      dst[base + 64 + p] = f2b(__cosf(proj) * 0.125f);
    }
  }
}

// ---------------- fused cooperative scan: chunk_sum | grid.sync | prefix | grid.sync | chunk_out ----
// Grid (NC, BH) = 512 blocks x 256 thr, 75.8 KB LDS -> 2 blocks/CU co-resident.
// vT tile persists in LDS across phases (same block = same (c,bh)).
__global__ __launch_bounds__(256) void scan_kernel(
    const ushort* __restrict__ pq, const ushort* __restrict__ pkg,
    const ushort* __restrict__ v, ushort* __restrict__ cS,
    float* __restrict__ cz, ushort* __restrict__ attn)
{
  cg::grid_group gridg = cg::this_grid();
  __shared__ ushort smem[37888];          // 75776 B
  ushort* vT    = smem;                   // [64][88]   (phases 1 & 3)
  ushort* pkT   = smem + 5632;            // [128][88]  (phase 1; overlaps pq_s/pk_s)
  ushort* pq_s  = smem + 5632;            // [64][136]  (phase 3)
  ushort* pk_s  = smem + 14336;           // [64][136]
  ushort* SpT_s = smem + 23040;           // [64][136]
  ushort* Am_s  = smem + 31744;           // [64][88]
  float*  zps   = (float*)(smem + 37376); // [128]
  float*  dens_s= zps + 128;              // [64]
  float*  inv_s = dens_s + 64;            // [64]

  const int c = blockIdx.x, bh = blockIdx.y, b = bh >> 3, h = bh & 7;
  const int tid = threadIdx.x;
  const int w = tid >> 6, lane = tid & 63;
  const int r = lane & 15, kb = lane >> 4;

  // ================= phase 1: chunk_sum =================
  for (int i = tid; i < CHK * 16; i += 256) {
    const int tt = i >> 4, k8 = (i & 15) * 8;
    const int n = (c * CHK + tt) * B_ + b;
    const ushort4 u0 = *(const ushort4*)(pkg + ((size_t)n * H_ + h) * K2 + k8);
    const ushort4 u1 = *(const ushort4*)(pkg + ((size_t)n * H_ + h) * K2 + k8 + 4);
    pkT[(k8+0)*88 + tt] = u0.x; pkT[(k8+1)*88 + tt] = u0.y;
    pkT[(k8+2)*88 + tt] = u0.z; pkT[(k8+3)*88 + tt] = u0.w;
    pkT[(k8+4)*88 + tt] = u1.x; pkT[(k8+5)*88 + tt] = u1.y;
    pkT[(k8+6)*88 + tt] = u1.z; pkT[(k8+7)*88 + tt] = u1.w;
  }
  for (int i = tid; i < CHK * 16; i += 256) {
    const int tt = i >> 4, d4 = (i & 15) * 4;
    const int n = (c * CHK + tt) * B_ + b;
    const ushort4 u = *(const ushort4*)(v + (size_t)n * E_ + h * D_ + d4);
    vT[(d4+0)*88 + tt] = u.x; vT[(d4+1)*88 + tt] = u.y;
    vT[(d4+2)*88 + tt] = u.z; vT[(d4+3)*88 + tt] = u.w;
  }
  __syncthreads();
  {
    const int m0s = w * 32;
    f32x4 acc1[2][4] = {};
    #pragma unroll
    for (int k0 = 0; k0 < CHK; k0 += 32) {
      const short8 a0 = *(const short8*)(&pkT[(m0s + r) * 88 + k0 + kb * 8]);
      const short8 a1 = *(const short8*)(&pkT[(m0s + 16 + r) * 88 + k0 + kb * 8]);
      #pragma unroll
      for (int nt = 0; nt < 4; ++nt) {
        const short8 bv = *(const short8*)(&vT[(nt * 16 + r) * 88 + k0 + kb * 8]);
        acc1[0][nt] = __builtin_amdgcn_mfma_f32_16x16x32_bf16(a0, bv, acc1[0][nt], 0, 0, 0);
        acc1[1][nt] = __builtin_amdgcn_mfma_f32_16x16x32_bf16(a1, bv, acc1[1][nt], 0, 0, 0);
      }
    }
    ushort* So = cS + (size_t)(c * BH + bh) * (K2 * D_);
    #pragma unroll
    for (int mt = 0; mt < 2; ++mt)
      #pragma unroll
      for (int nt = 0; nt < 4; ++nt)
        #pragma unroll
        for (int j = 0; j < 4; ++j)
          So[(m0s + mt * 16 + kb * 4 + j) * D_ + nt * 16 + r] = f2b(acc1[mt][nt][j]);
    if (tid < K2) {
      float zacc = 0.f;
      #pragma unroll
      for (int i2 = 0; i2 < CHK / 2; ++i2) {
        const uint u = *(const uint*)(&pkT[tid * 88 + i2 * 2]);
        zacc += lo16(u) + hi16(u);
      }
      cz[(size_t)(c * BH + bh) * K2 + tid] = zacc;
    }
  }
  gridg.sync();

  // ================= phase 2: exclusive prefix =================
  {
    const int fb = blockIdx.y * NC + blockIdx.x;      // 0..511
    const int gid = fb * 256 + tid;                   // 0..131071
    #pragma unroll
    for (int half = 0; half < 2; ++half) {
      const int e = gid + half * 131072;              // 0..262143
      const int bh2 = e >> 13, rem = e & 8191;
      float run = 0.f;
      #pragma unroll
      for (int c2 = 0; c2 < NC; ++c2) {
        ushort* p = cS + (((size_t)(c2 * BH + bh2)) << 13) + rem;
        const float t = b2f(*p); *p = f2b(run); run += t;
      }
    }
    if (gid < BH * K2) {
      const int zbh = gid >> 7, k2 = gid & 127;
      float rz = 0.f;
      #pragma unroll
      for (int c2 = 0; c2 < NC; ++c2) {
        float* pz = cz + (size_t)(c2 * BH + zbh) * K2 + k2;
        const float t = *pz; *pz = rz; rz += t;
      }
    }
  }
  gridg.sync();

  // ================= phase 3: chunk_out (vT still staged) =================
  for (int i = tid; i < CHK * 16; i += 256) {
    const int tt = i >> 4, k8 = (i & 15) * 8;
    const int n = (c * CHK + tt) * B_ + b;
    const size_t off = ((size_t)n * H_ + h) * K2 + k8;
    *(uint4*)(&pq_s[tt * 136 + k8]) = *(const uint4*)(pq + off);
    *(uint4*)(&pk_s[tt * 136 + k8]) = *(const uint4*)(pkg + off);
  }
  {
    const ushort* Spb = cS + (size_t)(c * BH + bh) * (K2 * D_);
    for (int i = tid; i < K2 * 8; i += 256) {
      const int k2 = i >> 3, d8 = (i & 7) * 8;
      const ushort4 s0 = *(const ushort4*)(Spb + k2 * D_ + d8);
      const ushort4 s1 = *(const ushort4*)(Spb + k2 * D_ + d8 + 4);
      SpT_s[(d8+0)*136 + k2] = s0.x; SpT_s[(d8+1)*136 + k2] = s0.y;
      SpT_s[(d8+2)*136 + k2] = s0.z; SpT_s[(d8+3)*136 + k2] = s0.w;
      SpT_s[(d8+4)*136 + k2] = s1.x; SpT_s[(d8+5)*136 + k2] = s1.y;
      SpT_s[(d8+6)*136 + k2] = s1.z; SpT_s[(d8+7)*136 + k2] = s1.w;
    }
  }
  if (tid < K2) zps[tid] = cz[(size_t)(c * BH + bh) * K2 + tid];
  __syncthreads();

  const int m0 = w * 16;
  f32x4 accA[4] = {};
  #pragma unroll
  for (int k0 = 0; k0 < K2; k0 += 32) {
    const short8 aq = *(const short8*)(&pq_s[(m0 + r) * 136 + k0 + kb * 8]);
    #pragma unroll
    for (int nt = 0; nt < 4; ++nt) {
      const short8 bk = *(const short8*)(&pk_s[(nt * 16 + r) * 136 + k0 + kb * 8]);
      accA[nt] = __builtin_amdgcn_mfma_f32_16x16x32_bf16(aq, bk, accA[nt], 0, 0, 0);
    }
  }
  float rs[4] = {0.f, 0.f, 0.f, 0.f};
  #pragma unroll
  for (int nt = 0; nt < 4; ++nt) {
    #pragma unroll
    for (int j = 0; j < 4; ++j) {
      const int row = kb * 4 + j, col = nt * 16 + r;
      float a = accA[nt][j];
      a = (col <= m0 + row) ? a : 0.f;
      rs[j] += a;
      Am_s[(m0 + row) * 88 + col] = f2b(a);
    }
  }
  #pragma unroll
  for (int off = 1; off < 16; off <<= 1) {
    rs[0] += __shfl_xor(rs[0], off, 64);
    rs[1] += __shfl_xor(rs[1], off, 64);
    rs[2] += __shfl_xor(rs[2], off, 64);
    rs[3] += __shfl_xor(rs[3], off, 64);
  }
  if (r == 0) {
    #pragma unroll
    for (int j = 0; j < 4; ++j) dens_s[m0 + kb * 4 + j] = rs[j];
  }
  f32x4 accO[4] = {};
  #pragma unroll
  for (int k0 = 0; k0 < CHK; k0 += 32) {
    const short8 aa = *(const short8*)(&Am_s[(m0 + r) * 88 + k0 + kb * 8]);
    #pragma unroll
    for (int nt = 0; nt < 4; ++nt) {
      const short8 bv = *(const short8*)(&vT[(nt * 16 + r) * 88 + k0 + kb * 8]);
      accO[nt] = __builtin_amdgcn_mfma_f32_16x16x32_bf16(aa, bv, accO[nt], 0, 0, 0);
    }
  }
  #pragma unroll
  for (int k0 = 0; k0 < K2; k0 += 32) {
    const short8 aq = *(const short8*)(&pq_s[(m0 + r) * 136 + k0 + kb * 8]);
    #pragma unroll
    for (int nt = 0; nt < 4; ++nt) {
      const short8 bs = *(const short8*)(&SpT_s[(nt * 16 + r) * 136 + k0 + kb * 8]);
      accO[nt] = __builtin_amdgcn_mfma_f32_16x16x32_bf16(aq, bs, accO[nt], 0, 0, 0);
    }
  }
  {
    const int t_loc = m0 + (lane >> 2), seg = lane & 3;
    float qz = 0.f;
    #pragma unroll
    for (int ii = 0; ii < 16; ++ii) {
      const uint u = *(const uint*)(&pq_s[t_loc * 136 + seg * 32 + ii * 2]);
      qz += lo16(u) * zps[seg * 32 + ii * 2] + hi16(u) * zps[seg * 32 + ii * 2 + 1];
    }
    qz += __shfl_xor(qz, 1, 64);
    qz += __shfl_xor(qz, 2, 64);
    if (seg == 0) inv_s[t_loc] = 1.0f / fmaxf(dens_s[t_loc] + qz, EPSV);
  }
  #pragma unroll
  for (int j = 0; j < 4; ++j) {
    const int row = m0 + kb * 4 + j;
    const float inv = inv_s[row];
    const int n = (c * CHK + row) * B_ + b;
    ushort* op = attn + (size_t)n * E_ + h * D_;
    #pragma unroll
    for (int nt = 0; nt < 4; ++nt) op[nt * 16 + r] = f2b(accO[nt][j] * inv);
  }
}

extern "C" void kernel_launch(void* const* d_in, const int* in_sizes, int n_in,
                              void* d_out, int out_size, void* d_ws, size_t ws_size,
                              hipStream_t stream) {
  const float* x  = (const float*)d_in[0];
  const float* rm = (const float*)d_in[1];
  const float* Wq = (const float*)d_in[2];
  const float* bq = (const float*)d_in[3];
  const float* Wk = (const float*)d_in[4];
  const float* bk = (const float*)d_in[5];
  const float* Wv = (const float*)d_in[6];
  const float* bv = (const float*)d_in[7];
  const float* Wo = (const float*)d_in[8];
  const float* bo = (const float*)d_in[9];
  float* out = (float*)d_out;

  ushort* xb  = (ushort*)d_ws;                    // [N,E] bf16
  ushort* wqb = xb + (size_t)N_ * E_;             // [E,E] bf16
  ushort* wkb = wqb + (size_t)E_ * E_;
  ushort* wvb = wkb + (size_t)E_ * E_;
  ushort* wob = wvb + (size_t)E_ * E_;
  ushort* rmb = wob + (size_t)E_ * E_;            // [H,P,D] bf16
  ushort* qb  = rmb + (size_t)H_ * P_ * D_;       // [N,E] bf16
  ushort* kb  = qb + (size_t)N_ * E_;             // [N,E] bf16
  ushort* vb  = kb + (size_t)N_ * E_;             // [N,E] bf16
  ushort* pqb = vb + (size_t)N_ * E_;             // [N,H,K2] bf16
  ushort* pkb = pqb + (size_t)N_ * H_ * K2;       // [N,H,K2] bf16
  ushort* attnb = pkb + (size_t)N_ * H_ * K2;     // [N,E] bf16
  ushort* cS = attnb + (size_t)N_ * E_;           // [NC,BH,K2,D] bf16 (8 MB)
  float* cz = (float*)(cS + (size_t)NC * BH * K2 * D_);  // [NC,BH,K2] f32

  cast_kernel<<<dim3(512, 6), dim3(256), 0, stream>>>(
      x, Wq, Wk, Wv, Wo, rm, xb, wqb, wkb, wvb, wob, rmb);
  gemm_qkv_kernel<<<dim3(N_ / 128, E_ / 64, 3), dim3(128), 0, stream>>>(
      xb, wqb, wkb, wvb, bq, bk, bv, qb, kb, vb);
  phi_kernel<<<dim3(N_ / 64, H_, 2), dim3(256), 0, stream>>>(qb, kb, rmb, pqb, pkb);
  {
    const ushort* a_pq = pqb; const ushort* a_pk = pkb; const ushort* a_v = vb;
    ushort* a_cS = cS; float* a_cz = cz; ushort* a_attn = attnb;
    void* args[6] = { (void*)&a_pq, (void*)&a_pk, (void*)&a_v,
                      (void*)&a_cS, (void*)&a_cz, (void*)&a_attn };
    hipLaunchCooperativeKernel((const void*)scan_kernel, dim3(NC, BH), dim3(256),
                               args, 0, stream);
  }
  gemm_out_kernel<<<dim3(N_ / 128, E_ / 64), dim3(128), 0, stream>>>(attnb, wob, bo, out);
}

// Round 11
// 68.979 us; speedup vs baseline: 2.8821x; 2.8821x over previous
//
#include <hip/hip_runtime.h>

#define T_ 1024
#define B_ 4
#define E_ 512
#define H_ 8
#define D_ 64
#define P_ 64
#define K2 128            // 2P
#define N_ (T_*B_)        // 4096 rows (t*B + b)
#define CHK 64            // scan chunk length
#define NC (T_/CHK)       // 16 chunks
#define BH (B_*H_)        // 32
#define EPSV 1e-6f

typedef unsigned int uint;
typedef unsigned short ushort;
typedef short short8 __attribute__((ext_vector_type(8)));   // 8 bf16 (MFMA A/B frag)
typedef float f32x4 __attribute__((ext_vector_type(4)));    // MFMA C/D frag

__device__ __forceinline__ float b2f(ushort u){ return __uint_as_float(((uint)u) << 16); }
__device__ __forceinline__ ushort f2b(float f){
  uint x = __float_as_uint(f);
  return (ushort)((x + 0x7fffu + ((x >> 16) & 1u)) >> 16);   // RNE
}
__device__ __forceinline__ float lo16(uint u){ return __uint_as_float(u << 16); }
__device__ __forceinline__ float hi16(uint u){ return __uint_as_float(u & 0xffff0000u); }
__device__ __forceinline__ void st(float* p, float v){ *p = v; }
__device__ __forceinline__ void st(ushort* p, float v){ *p = f2b(v); }

// async global->LDS, 16B per lane; LDS dest = wave-uniform base + lane*16 (m104)
__device__ __forceinline__ void gl16(const ushort* g, ushort* lds) {
  __builtin_amdgcn_global_load_lds(
      (const __attribute__((address_space(1))) uint*)g,
      (__attribute__((address_space(3))) uint*)lds, 16, 0, 0);
}

// ---------------- cast f32 -> bf16 (x + 4 weights + rm) ----------------
__global__ __launch_bounds__(256) void cast_kernel(
    const float* __restrict__ x, const float* __restrict__ wq, const float* __restrict__ wk,
    const float* __restrict__ wv, const float* __restrict__ wo, const float* __restrict__ rm,
    ushort* __restrict__ xb, ushort* __restrict__ wqb, ushort* __restrict__ wkb,
    ushort* __restrict__ wvb, ushort* __restrict__ wob, ushort* __restrict__ rmb)
{
  const float* src; ushort* dst; int n4;
  switch (blockIdx.y) {
    case 0:  src = x;  dst = xb;  n4 = N_ * E_ / 4; break;
    case 1:  src = wq; dst = wqb; n4 = E_ * E_ / 4; break;
    case 2:  src = wk; dst = wkb; n4 = E_ * E_ / 4; break;
    case 3:  src = wv; dst = wvb; n4 = E_ * E_ / 4; break;
    case 4:  src = wo; dst = wob; n4 = E_ * E_ / 4; break;
    default: src = rm; dst = rmb; n4 = H_ * P_ * D_ / 4; break;
  }
  const int stride = gridDim.x * 256;
  for (int i = blockIdx.x * 256 + threadIdx.x; i < n4; i += stride) {
    const float4 v = *(const float4*)(src + (size_t)i * 4);
    ushort4 o; o.x = f2b(v.x); o.y = f2b(v.y); o.z = f2b(v.z); o.w = f2b(v.w);
    *(ushort4*)(dst + (size_t)i * 4) = o;
  }
}

// ---------------- LDS-staged MFMA GEMM tile: 128x64, BK=32, 2 waves ----------------
template<typename OutT>
__device__ __forceinline__ void gemm_tile(
    const ushort* __restrict__ A, const ushort* __restrict__ W,
    const float* __restrict__ bias, OutT* __restrict__ out,
    const int row0, const int col0)
{
  __shared__ ushort sA[128 * 32];   // [row][k] rows of 64B, linear
  __shared__ ushort sB[64 * 32];
  const int tid = threadIdx.x, w = tid >> 6, lane = tid & 63;
  const int lrow = lane >> 2, lk8 = (lane & 3) * 8;
  const ushort* gA = A + (size_t)(row0 + w * 16 + lrow) * E_ + lk8;
  const ushort* gB = W + (size_t)(col0 + w * 16 + lrow) * E_ + lk8;
  ushort* lA = sA + w * 512;
  ushort* lB = sB + w * 512;
  const int r = lane & 15, kg = lane >> 4, kq = kg * 8;
  f32x4 acc[4][4] = {};
  for (int k0 = 0; k0 < E_; k0 += 32) {
    gl16(gA + k0,             lA);
    gl16(gA + k0 + 32 * E_,   lA + 1024);
    gl16(gA + k0 + 64 * E_,   lA + 2048);
    gl16(gA + k0 + 96 * E_,   lA + 3072);
    gl16(gB + k0,             lB);
    gl16(gB + k0 + 32 * E_,   lB + 1024);
    __syncthreads();
    short8 af[4], bf[4];
    #pragma unroll
    for (int m = 0; m < 4; ++m) af[m] = *(const short8*)(sA + (w * 64 + m * 16 + r) * 32 + kq);
    #pragma unroll
    for (int n = 0; n < 4; ++n) bf[n] = *(const short8*)(sB + (n * 16 + r) * 32 + kq);
    #pragma unroll
    for (int m = 0; m < 4; ++m)
      #pragma unroll
      for (int n = 0; n < 4; ++n)
        acc[m][n] = __builtin_amdgcn_mfma_f32_16x16x32_bf16(af[m], bf[n], acc[m][n], 0, 0, 0);
    __syncthreads();
  }
  float bs[4];
  #pragma unroll
  for (int n = 0; n < 4; ++n) bs[n] = bias[col0 + n * 16 + r];
  #pragma unroll
  for (int m = 0; m < 4; ++m) {
    #pragma unroll
    for (int j = 0; j < 4; ++j) {
      const int row_g = row0 + w * 64 + m * 16 + kg * 4 + j;
      #pragma unroll
      for (int n = 0; n < 4; ++n)
        st(out + (size_t)row_g * E_ + col0 + n * 16 + r, acc[m][n][j] + bs[n]);
    }
  }
}

__global__ __launch_bounds__(128) void gemm_qkv_kernel(
    const ushort* __restrict__ A,
    const ushort* __restrict__ wq, const ushort* __restrict__ wk, const ushort* __restrict__ wv,
    const float* __restrict__ bq, const float* __restrict__ bk, const float* __restrict__ bv,
    ushort* __restrict__ qb, ushort* __restrict__ kb, ushort* __restrict__ vb)
{
  const ushort* W; const float* bias; ushort* dst;
  if (blockIdx.z == 0)      { W = wq; bias = bq; dst = qb; }
  else if (blockIdx.z == 1) { W = wk; bias = bk; dst = kb; }
  else                      { W = wv; bias = bv; dst = vb; }
  gemm_tile<ushort>(A, W, bias, dst, blockIdx.x * 128, blockIdx.y * 64);
}

__global__ __launch_bounds__(128) void gemm_out_kernel(
    const ushort* __restrict__ A, const ushort* __restrict__ W,
    const float* __restrict__ bias, float* __restrict__ out)
{
  gemm_tile<float>(A, W, bias, out, blockIdx.x * 128, blockIdx.y * 64);
}

// ---------------- phi via MFMA ----------------
__global__ __launch_bounds__(256) void phi_kernel(
    const ushort* __restrict__ qb, const ushort* __restrict__ kb,
    const ushort* __restrict__ rmb, ushort* __restrict__ pq, ushort* __restrict__ pk)
{
  __shared__ ushort xq[64][72];    // q tile [n][d]
  __shared__ ushort rms[64][72];   // rm[h]  [p][d]
  __shared__ float inv_s[64];
  const int tid = threadIdx.x;
  const int h = blockIdx.y;
  const ushort* src = blockIdx.z ? kb : qb;
  ushort* dst = blockIdx.z ? pk : pq;
  const int n0 = blockIdx.x * 64;
  const int row = tid >> 2, seg = (tid & 3) * 16;
  {
    const ushort* gq = src + (size_t)(n0 + row) * E_ + h * D_ + seg;
    const ushort* gr = rmb + ((size_t)h * P_ + row) * D_ + seg;
    const uint4 q0 = *(const uint4*)(gq);
    const uint4 q1 = *(const uint4*)(gq + 8);
    *(uint4*)(&xq[row][seg])      = q0;
    *(uint4*)(&xq[row][seg + 8])  = q1;
    *(uint4*)(&rms[row][seg])     = *(const uint4*)(gr);
    *(uint4*)(&rms[row][seg + 8]) = *(const uint4*)(gr + 8);
    float s2 = 0.f;
    const uint* qw = (const uint*)&q0;
    #pragma unroll
    for (int i = 0; i < 4; ++i) { const float a = lo16(qw[i]), b = hi16(qw[i]); s2 += a*a + b*b; }
    const uint* qw1 = (const uint*)&q1;
    #pragma unroll
    for (int i = 0; i < 4; ++i) { const float a = lo16(qw1[i]), b = hi16(qw1[i]); s2 += a*a + b*b; }
    s2 += __shfl_xor(s2, 1, 64);
    s2 += __shfl_xor(s2, 2, 64);
    if ((tid & 3) == 0) inv_s[row] = 1.0f / fmaxf(sqrtf(s2), EPSV);
  }
  __syncthreads();
  const int w = tid >> 6, lane = tid & 63;
  const int r = lane & 15, kg = lane >> 4;
  const int m0 = w * 16;
  f32x4 acc[4] = {};
  #pragma unroll
  for (int k0 = 0; k0 < D_; k0 += 32) {
    const short8 a = *(const short8*)(&xq[m0 + r][k0 + kg * 8]);
    #pragma unroll
    for (int nt = 0; nt < 4; ++nt) {
      const short8 bfr = *(const short8*)(&rms[nt * 16 + r][k0 + kg * 8]);
      acc[nt] = __builtin_amdgcn_mfma_f32_16x16x32_bf16(a, bfr, acc[nt], 0, 0, 0);
    }
  }
  #pragma unroll
  for (int j = 0; j < 4; ++j) {
    const int rr = m0 + kg * 4 + j;
    const float inv = inv_s[rr];
    const size_t base = ((size_t)(n0 + rr) * H_ + h) * K2;
    #pragma unroll
    for (int nt = 0; nt < 4; ++nt) {
      const int p = nt * 16 + r;
      const float proj = acc[nt][j] * inv;
      dst[base + p]      = f2b(__sinf(proj) * 0.125f);   // P^-0.5
      dst[base + 64 + p] = f2b(__cosf(proj) * 0.125f);
    }
  }
}

// ---------------- chunk_sum via MFMA (bf16 out; per-chunk sums, NOT prefixed) ----------------
__global__ __launch_bounds__(256) void chunk_sum_kernel(
    const ushort* __restrict__ pk, const ushort* __restrict__ v,
    ushort* __restrict__ cS, float* __restrict__ cz)
{
  const int c = blockIdx.x, bh = blockIdx.y, b = bh >> 3, h = bh & 7;
  __shared__ ushort pkT[K2][88];   // [k2][tau]
  __shared__ ushort vT[D_][88];    // [d][tau]
  const int tid = threadIdx.x;
  for (int i = tid; i < CHK * 16; i += 256) {
    const int tt = i >> 4, k8 = (i & 15) * 8;
    const int n = (c * CHK + tt) * B_ + b;
    const ushort4 u0 = *(const ushort4*)(pk + ((size_t)n * H_ + h) * K2 + k8);
    const ushort4 u1 = *(const ushort4*)(pk + ((size_t)n * H_ + h) * K2 + k8 + 4);
    pkT[k8+0][tt] = u0.x; pkT[k8+1][tt] = u0.y; pkT[k8+2][tt] = u0.z; pkT[k8+3][tt] = u0.w;
    pkT[k8+4][tt] = u1.x; pkT[k8+5][tt] = u1.y; pkT[k8+6][tt] = u1.z; pkT[k8+7][tt] = u1.w;
  }
  for (int i = tid; i < CHK * 16; i += 256) {
    const int tt = i >> 4, d4 = (i & 15) * 4;
    const int n = (c * CHK + tt) * B_ + b;
    const ushort4 u = *(const ushort4*)(v + (size_t)n * E_ + h * D_ + d4);
    vT[d4+0][tt] = u.x; vT[d4+1][tt] = u.y; vT[d4+2][tt] = u.z; vT[d4+3][tt] = u.w;
  }
  __syncthreads();
  const int w = tid >> 6, lane = tid & 63;
  const int r = lane & 15, kb = lane >> 4;
  const int m0 = w * 32;
  f32x4 acc[2][4] = {};
  #pragma unroll
  for (int k0 = 0; k0 < CHK; k0 += 32) {
    const short8 a0 = *(const short8*)(&pkT[m0 + r][k0 + kb * 8]);
    const short8 a1 = *(const short8*)(&pkT[m0 + 16 + r][k0 + kb * 8]);
    #pragma unroll
    for (int nt = 0; nt < 4; ++nt) {
      const short8 bv = *(const short8*)(&vT[nt * 16 + r][k0 + kb * 8]);
      acc[0][nt] = __builtin_amdgcn_mfma_f32_16x16x32_bf16(a0, bv, acc[0][nt], 0, 0, 0);
      acc[1][nt] = __builtin_amdgcn_mfma_f32_16x16x32_bf16(a1, bv, acc[1][nt], 0, 0, 0);
    }
  }
  ushort* So = cS + (size_t)(c * BH + bh) * (K2 * D_);
  #pragma unroll
  for (int mt = 0; mt < 2; ++mt)
    #pragma unroll
    for (int nt = 0; nt < 4; ++nt)
      #pragma unroll
      for (int j = 0; j < 4; ++j)
        So[(m0 + mt * 16 + kb * 4 + j) * D_ + nt * 16 + r] = f2b(acc[mt][nt][j]);
  if (tid < K2) {
    float zacc = 0.f;
    #pragma unroll
    for (int i2 = 0; i2 < CHK / 2; ++i2) {
      const uint u = *(const uint*)(&pkT[tid][i2 * 2]);
      zacc += lo16(u) + hi16(u);
    }
    cz[(size_t)(c * BH + bh) * K2 + tid] = zacc;
  }
}

// ---------------- chunk_out via MFMA, with in-kernel exclusive prefix ----------------
// Sp = sum_{c'<c} cS[c'] accumulated in f32 registers (identical numerics to the
// old prefix kernel: f32 sum of bf16 chunk sums, one bf16 rounding before MFMA).
__global__ __launch_bounds__(256) void chunk_out_kernel(
    const ushort* __restrict__ pq, const ushort* __restrict__ pkg,
    const ushort* __restrict__ v, const ushort* __restrict__ cS,
    const float* __restrict__ cz, ushort* __restrict__ attn)
{
  const int c = blockIdx.x, bh = blockIdx.y, b = bh >> 3, h = bh & 7;
  __shared__ ushort pq_s[CHK][136];
  __shared__ ushort pk_s[CHK][136];
  __shared__ ushort SpT_s[D_][136];   // [d][k2] bf16
  __shared__ ushort vT_s[D_][88];     // [d][tau]
  __shared__ ushort Am_s[CHK][88];    // masked A bf16 [t][tau]
  __shared__ float zps[K2];
  __shared__ float dens_s[CHK];
  __shared__ float inv_s[CHK];
  const int tid = threadIdx.x;
  for (int i = tid; i < CHK * 16; i += 256) {
    const int tt = i >> 4, k8 = (i & 15) * 8;
    const int n = (c * CHK + tt) * B_ + b;
    const size_t off = ((size_t)n * H_ + h) * K2 + k8;
    *(uint4*)(&pq_s[tt][k8]) = *(const uint4*)(pq + off);
    *(uint4*)(&pk_s[tt][k8]) = *(const uint4*)(pkg + off);
  }
  for (int i = tid; i < CHK * 16; i += 256) {
    const int tt = i >> 4, d4 = (i & 15) * 4;
    const int n = (c * CHK + tt) * B_ + b;
    const ushort4 u = *(const ushort4*)(v + (size_t)n * E_ + h * D_ + d4);
    vT_s[d4+0][tt] = u.x; vT_s[d4+1][tt] = u.y; vT_s[d4+2][tt] = u.z; vT_s[d4+3][tt] = u.w;
  }
  // ---- Sp prefix accumulation (replaces the prefix_kernel dispatch) ----
  {
    float accS[4][8];
    #pragma unroll
    for (int it = 0; it < 4; ++it)
      #pragma unroll
      for (int l = 0; l < 8; ++l) accS[it][l] = 0.f;
    for (int cp = 0; cp < c; ++cp) {
      const ushort* Sc = cS + (size_t)(cp * BH + bh) * (K2 * D_);
      #pragma unroll
      for (int it = 0; it < 4; ++it) {
        const int i = it * 256 + tid;
        const int k2 = i >> 3, d8 = (i & 7) * 8;
        const ushort4 s0 = *(const ushort4*)(Sc + k2 * D_ + d8);
        const ushort4 s1 = *(const ushort4*)(Sc + k2 * D_ + d8 + 4);
        accS[it][0] += b2f(s0.x); accS[it][1] += b2f(s0.y);
        accS[it][2] += b2f(s0.z); accS[it][3] += b2f(s0.w);
        accS[it][4] += b2f(s1.x); accS[it][5] += b2f(s1.y);
        accS[it][6] += b2f(s1.z); accS[it][7] += b2f(s1.w);
      }
    }
    #pragma unroll
    for (int it = 0; it < 4; ++it) {
      const int i = it * 256 + tid;
      const int k2 = i >> 3, d8 = (i & 7) * 8;
      #pragma unroll
      for (int l = 0; l < 8; ++l)
        SpT_s[d8 + l][k2] = f2b(accS[it][l]);
    }
  }
  if (tid < K2) {
    float z = 0.f;
    for (int cp = 0; cp < c; ++cp)
      z += cz[(size_t)(cp * BH + bh) * K2 + tid];
    zps[tid] = z;
  }
  __syncthreads();

  const int w = tid >> 6, lane = tid & 63;
  const int r = lane & 15, kb = lane >> 4;
  const int m0 = w * 16;
  f32x4 accA[4] = {};
  #pragma unroll
  for (int k0 = 0; k0 < K2; k0 += 32) {
    const short8 aq = *(const short8*)(&pq_s[m0 + r][k0 + kb * 8]);
    #pragma unroll
    for (int nt = 0; nt < 4; ++nt) {
      const short8 bk = *(const short8*)(&pk_s[nt * 16 + r][k0 + kb * 8]);
      accA[nt] = __builtin_amdgcn_mfma_f32_16x16x32_bf16(aq, bk, accA[nt], 0, 0, 0);
    }
  }
  float rs[4] = {0.f, 0.f, 0.f, 0.f};
  #pragma unroll
  for (int nt = 0; nt < 4; ++nt) {
    #pragma unroll
    for (int j = 0; j < 4; ++j) {
      const int row = kb * 4 + j, col = nt * 16 + r;
      float a = accA[nt][j];
      a = (col <= m0 + row) ? a : 0.f;
      rs[j] += a;
      Am_s[m0 + row][col] = f2b(a);
    }
  }
  #pragma unroll
  for (int off = 1; off < 16; off <<= 1) {
    rs[0] += __shfl_xor(rs[0], off, 64);
    rs[1] += __shfl_xor(rs[1], off, 64);
    rs[2] += __shfl_xor(rs[2], off, 64);
    rs[3] += __shfl_xor(rs[3], off, 64);
  }
  if (r == 0) {
    #pragma unroll
    for (int j = 0; j < 4; ++j) dens_s[m0 + kb * 4 + j] = rs[j];
  }
  f32x4 accO[4] = {};
  #pragma unroll
  for (int k0 = 0; k0 < CHK; k0 += 32) {
    const short8 aa = *(const short8*)(&Am_s[m0 + r][k0 + kb * 8]);
    #pragma unroll
    for (int nt = 0; nt < 4; ++nt) {
      const short8 bv = *(const short8*)(&vT_s[nt * 16 + r][k0 + kb * 8]);
      accO[nt] = __builtin_amdgcn_mfma_f32_16x16x32_bf16(aa, bv, accO[nt], 0, 0, 0);
    }
  }
  #pragma unroll
  for (int k0 = 0; k0 < K2; k0 += 32) {
    const short8 aq = *(const short8*)(&pq_s[m0 + r][k0 + kb * 8]);
    #pragma unroll
    for (int nt = 0; nt < 4; ++nt) {
      const short8 bs = *(const short8*)(&SpT_s[nt * 16 + r][k0 + kb * 8]);
      accO[nt] = __builtin_amdgcn_mfma_f32_16x16x32_bf16(aq, bs, accO[nt], 0, 0, 0);
    }
  }
  {
    const int t_loc = m0 + (lane >> 2), seg = lane & 3;
    float qz = 0.f;
    #pragma unroll
    for (int ii = 0; ii < 16; ++ii) {
      const uint u = *(const uint*)(&pq_s[t_loc][seg * 32 + ii * 2]);
      qz += lo16(u) * zps[seg * 32 + ii * 2] + hi16(u) * zps[seg * 32 + ii * 2 + 1];
    }
    qz += __shfl_xor(qz, 1, 64);
    qz += __shfl_xor(qz, 2, 64);
    if (seg == 0) inv_s[t_loc] = 1.0f / fmaxf(dens_s[t_loc] + qz, EPSV);
  }
  #pragma unroll
  for (int j = 0; j < 4; ++j) {
    const int row = m0 + kb * 4 + j;
    const float inv = inv_s[row];
    const int n = (c * CHK + row) * B_ + b;
    ushort* op = attn + (size_t)n * E_ + h * D_;
    #pragma unroll
    for (int nt = 0; nt < 4; ++nt) op[nt * 16 + r] = f2b(accO[nt][j] * inv);
  }
}

extern "C" void kernel_launch(void* const* d_in, const int* in_sizes, int n_in,
                              void* d_out, int out_size, void* d_ws, size_t ws_size,
                              hipStream_t stream) {
  const float* x  = (const float*)d_in[0];
  const float* rm = (const float*)d_in[1];
  const float* Wq = (const float*)d_in[2];
  const float* bq = (const float*)d_in[3];
  const float* Wk = (const float*)d_in[4];
  const float* bk = (const float*)d_in[5];
  const float* Wv = (const float*)d_in[6];
  const float* bv = (const float*)d_in[7];
  const float* Wo = (const float*)d_in[8];
  const float* bo = (const float*)d_in[9];
  float* out = (float*)d_out;

  ushort* xb  = (ushort*)d_ws;                    // [N,E] bf16
  ushort* wqb = xb + (size_t)N_ * E_;             // [E,E] bf16
  ushort* wkb = wqb + (size_t)E_ * E_;
  ushort* wvb = wkb + (size_t)E_ * E_;
  ushort* wob = wvb + (size_t)E_ * E_;
  ushort* rmb = wob + (size_t)E_ * E_;            // [H,P,D] bf16
  ushort* qb  = rmb + (size_t)H_ * P_ * D_;       // [N,E] bf16
  ushort* kb  = qb + (size_t)N_ * E_;             // [N,E] bf16
  ushort* vb  = kb + (size_t)N_ * E_;             // [N,E] bf16
  ushort* pqb = vb + (size_t)N_ * E_;             // [N,H,K2] bf16
  ushort* pkb = pqb + (size_t)N_ * H_ * K2;       // [N,H,K2] bf16
  ushort* attnb = pkb + (size_t)N_ * H_ * K2;     // [N,E] bf16
  ushort* cS = attnb + (size_t)N_ * E_;           // [NC,BH,K2,D] bf16 (8 MB, per-chunk sums)
  float* cz = (float*)(cS + (size_t)NC * BH * K2 * D_);  // [NC,BH,K2] f32

  cast_kernel<<<dim3(512, 6), dim3(256), 0, stream>>>(
      x, Wq, Wk, Wv, Wo, rm, xb, wqb, wkb, wvb, wob, rmb);
  gemm_qkv_kernel<<<dim3(N_ / 128, E_ / 64, 3), dim3(128), 0, stream>>>(
      xb, wqb, wkb, wvb, bq, bk, bv, qb, kb, vb);
  phi_kernel<<<dim3(N_ / 64, H_, 2), dim3(256), 0, stream>>>(qb, kb, rmb, pqb, pkb);
  chunk_sum_kernel<<<dim3(NC, BH), dim3(256), 0, stream>>>(pkb, vb, cS, cz);
  chunk_out_kernel<<<dim3(NC, BH), dim3(256), 0, stream>>>(pqb, pkb, vb, cS, cz, attnb);
  gemm_out_kernel<<<dim3(N_ / 128, E_ / 64), dim3(128), 0, stream>>>(attnb, wob, bo, out);
}

// Round 12
// 62.609 us; speedup vs baseline: 3.1754x; 1.1017x over previous
//
#include <hip/hip_runtime.h>

#define T_ 1024
#define B_ 4
#define E_ 512
#define H_ 8
#define D_ 64
#define P_ 64
#define K2 128            // 2P
#define N_ (T_*B_)        // 4096 rows (t*B + b)
#define CHK 64            // scan chunk length
#define NC (T_/CHK)       // 16 chunks
#define BH (B_*H_)        // 32
#define EPSV 1e-6f

typedef unsigned int uint;
typedef unsigned short ushort;
typedef short short8 __attribute__((ext_vector_type(8)));   // 8 bf16 (MFMA A/B frag)
typedef float f32x4 __attribute__((ext_vector_type(4)));    // MFMA C/D frag

__device__ __forceinline__ float b2f(ushort u){ return __uint_as_float(((uint)u) << 16); }
__device__ __forceinline__ ushort f2b(float f){
  uint x = __float_as_uint(f);
  return (ushort)((x + 0x7fffu + ((x >> 16) & 1u)) >> 16);   // RNE
}
__device__ __forceinline__ float lo16(uint u){ return __uint_as_float(u << 16); }
__device__ __forceinline__ float hi16(uint u){ return __uint_as_float(u & 0xffff0000u); }
__device__ __forceinline__ void st(float* p, float v){ *p = v; }
__device__ __forceinline__ void st(ushort* p, float v){ *p = f2b(v); }

// async global->LDS, 16B per lane; LDS dest = wave-uniform base + lane*16 (m104)
__device__ __forceinline__ void gl16(const ushort* g, ushort* lds) {
  __builtin_amdgcn_global_load_lds(
      (const __attribute__((address_space(1))) uint*)g,
      (__attribute__((address_space(3))) uint*)lds, 16, 0, 0);
}

// ---------------- cast f32 -> bf16 (x + 4 weights + rm) ----------------
__global__ __launch_bounds__(256) void cast_kernel(
    const float* __restrict__ x, const float* __restrict__ wq, const float* __restrict__ wk,
    const float* __restrict__ wv, const float* __restrict__ wo, const float* __restrict__ rm,
    ushort* __restrict__ xb, ushort* __restrict__ wqb, ushort* __restrict__ wkb,
    ushort* __restrict__ wvb, ushort* __restrict__ wob, ushort* __restrict__ rmb)
{
  const float* src; ushort* dst; int n4;
  switch (blockIdx.y) {
    case 0:  src = x;  dst = xb;  n4 = N_ * E_ / 4; break;
    case 1:  src = wq; dst = wqb; n4 = E_ * E_ / 4; break;
    case 2:  src = wk; dst = wkb; n4 = E_ * E_ / 4; break;
    case 3:  src = wv; dst = wvb; n4 = E_ * E_ / 4; break;
    case 4:  src = wo; dst = wob; n4 = E_ * E_ / 4; break;
    default: src = rm; dst = rmb; n4 = H_ * P_ * D_ / 4; break;
  }
  const int stride = gridDim.x * 256;
  for (int i = blockIdx.x * 256 + threadIdx.x; i < n4; i += stride) {
    const float4 v = *(const float4*)(src + (size_t)i * 4);
    ushort4 o; o.x = f2b(v.x); o.y = f2b(v.y); o.z = f2b(v.z); o.w = f2b(v.w);
    *(ushort4*)(dst + (size_t)i * 4) = o;
  }
}

// ---------------- LDS-staged MFMA GEMM tile: 128x64, BK=32, FOUR waves ----------------
// 4 waves/block (vs 2): 12 waves/CU at grid 768 -> 2x TLP for latency hiding.
// Wave w computes output rows [w*32, w*32+32); stages its own A rows (2 gl16) + B share (1 gl16).
template<typename OutT>
__device__ __forceinline__ void gemm_tile(
    const ushort* __restrict__ A, const ushort* __restrict__ W,
    const float* __restrict__ bias, OutT* __restrict__ out,
    const int row0, const int col0)
{
  __shared__ ushort sA[128 * 32];   // [row][32] rows of 64B, linear
  __shared__ ushort sB[64 * 32];
  const int tid = threadIdx.x, w = tid >> 6, lane = tid & 63;
  const int lrow = lane >> 2, lk8 = (lane & 3) * 8;   // 16 rows per 1KB issue
  const ushort* gA = A + (size_t)(row0 + w * 32 + lrow) * E_ + lk8;
  const ushort* gB = W + (size_t)(col0 + w * 16 + lrow) * E_ + lk8;
  ushort* lA = sA + w * 1024;       // wave w's 32 A-rows
  ushort* lB = sB + w * 512;        // wave w's 16 B-rows
  const int r = lane & 15, kg = lane >> 4, kq = kg * 8;
  f32x4 acc[2][4] = {};
  for (int k0 = 0; k0 < E_; k0 += 32) {
    gl16(gA + k0,           lA);
    gl16(gA + k0 + 16 * E_, lA + 512);
    gl16(gB + k0,           lB);
    __syncthreads();
    short8 af[2], bf[4];
    #pragma unroll
    for (int m = 0; m < 2; ++m) af[m] = *(const short8*)(sA + (w * 32 + m * 16 + r) * 32 + kq);
    #pragma unroll
    for (int n = 0; n < 4; ++n) bf[n] = *(const short8*)(sB + (n * 16 + r) * 32 + kq);
    #pragma unroll
    for (int m = 0; m < 2; ++m)
      #pragma unroll
      for (int n = 0; n < 4; ++n)
        acc[m][n] = __builtin_amdgcn_mfma_f32_16x16x32_bf16(af[m], bf[n], acc[m][n], 0, 0, 0);
    __syncthreads();
  }
  float bs[4];
  #pragma unroll
  for (int n = 0; n < 4; ++n) bs[n] = bias[col0 + n * 16 + r];
  #pragma unroll
  for (int m = 0; m < 2; ++m) {
    #pragma unroll
    for (int j = 0; j < 4; ++j) {
      const int row_g = row0 + w * 32 + m * 16 + kg * 4 + j;
      #pragma unroll
      for (int n = 0; n < 4; ++n)
        st(out + (size_t)row_g * E_ + col0 + n * 16 + r, acc[m][n][j] + bs[n]);
    }
  }
}

__global__ __launch_bounds__(256) void gemm_qkv_kernel(
    const ushort* __restrict__ A,
    const ushort* __restrict__ wq, const ushort* __restrict__ wk, const ushort* __restrict__ wv,
    const float* __restrict__ bq, const float* __restrict__ bk, const float* __restrict__ bv,
    ushort* __restrict__ qb, ushort* __restrict__ kb, ushort* __restrict__ vb)
{
  const ushort* W; const float* bias; ushort* dst;
  if (blockIdx.z == 0)      { W = wq; bias = bq; dst = qb; }
  else if (blockIdx.z == 1) { W = wk; bias = bk; dst = kb; }
  else                      { W = wv; bias = bv; dst = vb; }
  gemm_tile<ushort>(A, W, bias, dst, blockIdx.x * 128, blockIdx.y * 64);
}

__global__ __launch_bounds__(256) void gemm_out_kernel(
    const ushort* __restrict__ A, const ushort* __restrict__ W,
    const float* __restrict__ bias, float* __restrict__ out)
{
  gemm_tile<float>(A, W, bias, out, blockIdx.x * 128, blockIdx.y * 64);
}

// ---------------- phi via MFMA ----------------
__global__ __launch_bounds__(256) void phi_kernel(
    const ushort* __restrict__ qb, const ushort* __restrict__ kb,
    const ushort* __restrict__ rmb, ushort* __restrict__ pq, ushort* __restrict__ pk)
{
  __shared__ ushort xq[64][72];    // q tile [n][d]
  __shared__ ushort rms[64][72];   // rm[h]  [p][d]
  __shared__ float inv_s[64];
  const int tid = threadIdx.x;
  const int h = blockIdx.y;
  const ushort* src = blockIdx.z ? kb : qb;
  ushort* dst = blockIdx.z ? pk : pq;
  const int n0 = blockIdx.x * 64;
  const int row = tid >> 2, seg = (tid & 3) * 16;
  {
    const ushort* gq = src + (size_t)(n0 + row) * E_ + h * D_ + seg;
    const ushort* gr = rmb + ((size_t)h * P_ + row) * D_ + seg;
    const uint4 q0 = *(const uint4*)(gq);
    const uint4 q1 = *(const uint4*)(gq + 8);
    *(uint4*)(&xq[row][seg])      = q0;
    *(uint4*)(&xq[row][seg + 8])  = q1;
    *(uint4*)(&rms[row][seg])     = *(const uint4*)(gr);
    *(uint4*)(&rms[row][seg + 8]) = *(const uint4*)(gr + 8);
    float s2 = 0.f;
    const uint* qw = (const uint*)&q0;
    #pragma unroll
    for (int i = 0; i < 4; ++i) { const float a = lo16(qw[i]), b = hi16(qw[i]); s2 += a*a + b*b; }
    const uint* qw1 = (const uint*)&q1;
    #pragma unroll
    for (int i = 0; i < 4; ++i) { const float a = lo16(qw1[i]), b = hi16(qw1[i]); s2 += a*a + b*b; }
    s2 += __shfl_xor(s2, 1, 64);
    s2 += __shfl_xor(s2, 2, 64);
    if ((tid & 3) == 0) inv_s[row] = 1.0f / fmaxf(sqrtf(s2), EPSV);
  }
  __syncthreads();
  const int w = tid >> 6, lane = tid & 63;
  const int r = lane & 15, kg = lane >> 4;
  const int m0 = w * 16;
  f32x4 acc[4] = {};
  #pragma unroll
  for (int k0 = 0; k0 < D_; k0 += 32) {
    const short8 a = *(const short8*)(&xq[m0 + r][k0 + kg * 8]);
    #pragma unroll
    for (int nt = 0; nt < 4; ++nt) {
      const short8 bfr = *(const short8*)(&rms[nt * 16 + r][k0 + kg * 8]);
      acc[nt] = __builtin_amdgcn_mfma_f32_16x16x32_bf16(a, bfr, acc[nt], 0, 0, 0);
    }
  }
  #pragma unroll
  for (int j = 0; j < 4; ++j) {
    const int rr = m0 + kg * 4 + j;
    const float inv = inv_s[rr];
    const size_t base = ((size_t)(n0 + rr) * H_ + h) * K2;
    #pragma unroll
    for (int nt = 0; nt < 4; ++nt) {
      const int p = nt * 16 + r;
      const float proj = acc[nt][j] * inv;
      dst[base + p]      = f2b(__sinf(proj) * 0.125f);   // P^-0.5
      dst[base + 64 + p] = f2b(__cosf(proj) * 0.125f);
    }
  }
}

// ---------------- chunk_sum via MFMA (bf16 out) ----------------
__global__ __launch_bounds__(256) void chunk_sum_kernel(
    const ushort* __restrict__ pk, const ushort* __restrict__ v,
    ushort* __restrict__ cS, float* __restrict__ cz)
{
  const int c = blockIdx.x, bh = blockIdx.y, b = bh >> 3, h = bh & 7;
  __shared__ ushort pkT[K2][88];   // [k2][tau]
  __shared__ ushort vT[D_][88];    // [d][tau]
  const int tid = threadIdx.x;
  for (int i = tid; i < CHK * 16; i += 256) {
    const int tt = i >> 4, k8 = (i & 15) * 8;
    const int n = (c * CHK + tt) * B_ + b;
    const ushort4 u0 = *(const ushort4*)(pk + ((size_t)n * H_ + h) * K2 + k8);
    const ushort4 u1 = *(const ushort4*)(pk + ((size_t)n * H_ + h) * K2 + k8 + 4);
    pkT[k8+0][tt] = u0.x; pkT[k8+1][tt] = u0.y; pkT[k8+2][tt] = u0.z; pkT[k8+3][tt] = u0.w;
    pkT[k8+4][tt] = u1.x; pkT[k8+5][tt] = u1.y; pkT[k8+6][tt] = u1.z; pkT[k8+7][tt] = u1.w;
  }
  for (int i = tid; i < CHK * 16; i += 256) {
    const int tt = i >> 4, d4 = (i & 15) * 4;
    const int n = (c * CHK + tt) * B_ + b;
    const ushort4 u = *(const ushort4*)(v + (size_t)n * E_ + h * D_ + d4);
    vT[d4+0][tt] = u.x; vT[d4+1][tt] = u.y; vT[d4+2][tt] = u.z; vT[d4+3][tt] = u.w;
  }
  __syncthreads();
  const int w = tid >> 6, lane = tid & 63;
  const int r = lane & 15, kb = lane >> 4;
  const int m0 = w * 32;
  f32x4 acc[2][4] = {};
  #pragma unroll
  for (int k0 = 0; k0 < CHK; k0 += 32) {
    const short8 a0 = *(const short8*)(&pkT[m0 + r][k0 + kb * 8]);
    const short8 a1 = *(const short8*)(&pkT[m0 + 16 + r][k0 + kb * 8]);
    #pragma unroll
    for (int nt = 0; nt < 4; ++nt) {
      const short8 bv = *(const short8*)(&vT[nt * 16 + r][k0 + kb * 8]);
      acc[0][nt] = __builtin_amdgcn_mfma_f32_16x16x32_bf16(a0, bv, acc[0][nt], 0, 0, 0);
      acc[1][nt] = __builtin_amdgcn_mfma_f32_16x16x32_bf16(a1, bv, acc[1][nt], 0, 0, 0);
    }
  }
  ushort* So = cS + (size_t)(c * BH + bh) * (K2 * D_);
  #pragma unroll
  for (int mt = 0; mt < 2; ++mt)
    #pragma unroll
    for (int nt = 0; nt < 4; ++nt)
      #pragma unroll
      for (int j = 0; j < 4; ++j)
        So[(m0 + mt * 16 + kb * 4 + j) * D_ + nt * 16 + r] = f2b(acc[mt][nt][j]);
  if (tid < K2) {
    float zacc = 0.f;
    #pragma unroll
    for (int i2 = 0; i2 < CHK / 2; ++i2) {
      const uint u = *(const uint*)(&pkT[tid][i2 * 2]);
      zacc += lo16(u) + hi16(u);
    }
    cz[(size_t)(c * BH + bh) * K2 + tid] = zacc;
  }
}

// ---------------- exclusive prefix over chunks (bf16 data, f32 accumulator) ----------------
__global__ __launch_bounds__(256) void prefix_kernel(
    ushort* __restrict__ cS, float* __restrict__ cz)
{
  const int gid = blockIdx.x * 256 + threadIdx.x;   // 262144 threads
  const int bh = gid >> 13, rem = gid & 8191;
  float run = 0.f;
  #pragma unroll
  for (int c = 0; c < NC; ++c) {
    ushort* p = cS + (((size_t)(c * BH + bh)) << 13) + rem;
    const float t = b2f(*p); *p = f2b(run); run += t;
  }
  if (gid < BH * K2) {
    const int zbh = gid >> 7, k2 = gid & 127;
    float rz = 0.f;
    #pragma unroll
    for (int c = 0; c < NC; ++c) {
      float* pz = cz + (size_t)(c * BH + zbh) * K2 + k2;
      const float t = *pz; *pz = rz; rz += t;
    }
  }
}

// ---------------- chunk_out via MFMA (Sp bf16) ----------------
__global__ __launch_bounds__(256) void chunk_out_kernel(
    const ushort* __restrict__ pq, const ushort* __restrict__ pkg,
    const ushort* __restrict__ v, const ushort* __restrict__ Sp,
    const float* __restrict__ zp, ushort* __restrict__ attn)
{
  const int c = blockIdx.x, bh = blockIdx.y, b = bh >> 3, h = bh & 7;
  __shared__ ushort pq_s[CHK][136];
  __shared__ ushort pk_s[CHK][136];
  __shared__ ushort SpT_s[D_][136];   // [d][k2] bf16
  __shared__ ushort vT_s[D_][88];     // [d][tau]
  __shared__ ushort Am_s[CHK][88];    // masked A bf16 [t][tau]
  __shared__ float zps[K2];
  __shared__ float dens_s[CHK];
  __shared__ float inv_s[CHK];
  const int tid = threadIdx.x;
  for (int i = tid; i < CHK * 16; i += 256) {
    const int tt = i >> 4, k8 = (i & 15) * 8;
    const int n = (c * CHK + tt) * B_ + b;
    const size_t off = ((size_t)n * H_ + h) * K2 + k8;
    *(uint4*)(&pq_s[tt][k8]) = *(const uint4*)(pq + off);
    *(uint4*)(&pk_s[tt][k8]) = *(const uint4*)(pkg + off);
  }
  for (int i = tid; i < CHK * 16; i += 256) {
    const int tt = i >> 4, d4 = (i & 15) * 4;
    const int n = (c * CHK + tt) * B_ + b;
    const ushort4 u = *(const ushort4*)(v + (size_t)n * E_ + h * D_ + d4);
    vT_s[d4+0][tt] = u.x; vT_s[d4+1][tt] = u.y; vT_s[d4+2][tt] = u.z; vT_s[d4+3][tt] = u.w;
  }
  const ushort* Spb = Sp + (size_t)(c * BH + bh) * (K2 * D_);
  for (int i = tid; i < K2 * 8; i += 256) {
    const int k2 = i >> 3, d8 = (i & 7) * 8;
    const ushort4 s0 = *(const ushort4*)(Spb + k2 * D_ + d8);
    const ushort4 s1 = *(const ushort4*)(Spb + k2 * D_ + d8 + 4);
    SpT_s[d8+0][k2] = s0.x; SpT_s[d8+1][k2] = s0.y;
    SpT_s[d8+2][k2] = s0.z; SpT_s[d8+3][k2] = s0.w;
    SpT_s[d8+4][k2] = s1.x; SpT_s[d8+5][k2] = s1.y;
    SpT_s[d8+6][k2] = s1.z; SpT_s[d8+7][k2] = s1.w;
  }
  if (tid < K2) zps[tid] = zp[(size_t)(c * BH + bh) * K2 + tid];
  __syncthreads();

  const int w = tid >> 6, lane = tid & 63;
  const int r = lane & 15, kb = lane >> 4;
  const int m0 = w * 16;
  f32x4 accA[4] = {};
  #pragma unroll
  for (int k0 = 0; k0 < K2; k0 += 32) {
    const short8 aq = *(const short8*)(&pq_s[m0 + r][k0 + kb * 8]);
    #pragma unroll
    for (int nt = 0; nt < 4; ++nt) {
      const short8 bk = *(const short8*)(&pk_s[nt * 16 + r][k0 + kb * 8]);
      accA[nt] = __builtin_amdgcn_mfma_f32_16x16x32_bf16(aq, bk, accA[nt], 0, 0, 0);
    }
  }
  float rs[4] = {0.f, 0.f, 0.f, 0.f};
  #pragma unroll
  for (int nt = 0; nt < 4; ++nt) {
    #pragma unroll
    for (int j = 0; j < 4; ++j) {
      const int row = kb * 4 + j, col = nt * 16 + r;
      float a = accA[nt][j];
      a = (col <= m0 + row) ? a : 0.f;
      rs[j] += a;
      Am_s[m0 + row][col] = f2b(a);
    }
  }
  #pragma unroll
  for (int off = 1; off < 16; off <<= 1) {
    rs[0] += __shfl_xor(rs[0], off, 64);
    rs[1] += __shfl_xor(rs[1], off, 64);
    rs[2] += __shfl_xor(rs[2], off, 64);
    rs[3] += __shfl_xor(rs[3], off, 64);
  }
  if (r == 0) {
    #pragma unroll
    for (int j = 0; j < 4; ++j) dens_s[m0 + kb * 4 + j] = rs[j];
  }
  f32x4 accO[4] = {};
  #pragma unroll
  for (int k0 = 0; k0 < CHK; k0 += 32) {
    const short8 aa = *(const short8*)(&Am_s[m0 + r][k0 + kb * 8]);
    #pragma unroll
    for (int nt = 0; nt < 4; ++nt) {
      const short8 bv = *(const short8*)(&vT_s[nt * 16 + r][k0 + kb * 8]);
      accO[nt] = __builtin_amdgcn_mfma_f32_16x16x32_bf16(aa, bv, accO[nt], 0, 0, 0);
    }
  }
  #pragma unroll
  for (int k0 = 0; k0 < K2; k0 += 32) {
    const short8 aq = *(const short8*)(&pq_s[m0 + r][k0 + kb * 8]);
    #pragma unroll
    for (int nt = 0; nt < 4; ++nt) {
      const short8 bs = *(const short8*)(&SpT_s[nt * 16 + r][k0 + kb * 8]);
      accO[nt] = __builtin_amdgcn_mfma_f32_16x16x32_bf16(aq, bs, accO[nt], 0, 0, 0);
    }
  }
  {
    const int t_loc = m0 + (lane >> 2), seg = lane & 3;
    float qz = 0.f;
    #pragma unroll
    for (int ii = 0; ii < 16; ++ii) {
      const uint u = *(const uint*)(&pq_s[t_loc][seg * 32 + ii * 2]);
      qz += lo16(u) * zps[seg * 32 + ii * 2] + hi16(u) * zps[seg * 32 + ii * 2 + 1];
    }
    qz += __shfl_xor(qz, 1, 64);
    qz += __shfl_xor(qz, 2, 64);
    if (seg == 0) inv_s[t_loc] = 1.0f / fmaxf(dens_s[t_loc] + qz, EPSV);
  }
  #pragma unroll
  for (int j = 0; j < 4; ++j) {
    const int row = m0 + kb * 4 + j;
    const float inv = inv_s[row];
    const int n = (c * CHK + row) * B_ + b;
    ushort* op = attn + (size_t)n * E_ + h * D_;
    #pragma unroll
    for (int nt = 0; nt < 4; ++nt) op[nt * 16 + r] = f2b(accO[nt][j] * inv);
  }
}

extern "C" void kernel_launch(void* const* d_in, const int* in_sizes, int n_in,
                              void* d_out, int out_size, void* d_ws, size_t ws_size,
                              hipStream_t stream) {
  const float* x  = (const float*)d_in[0];
  const float* rm = (const float*)d_in[1];
  const float* Wq = (const float*)d_in[2];
  const float* bq = (const float*)d_in[3];
  const float* Wk = (const float*)d_in[4];
  const float* bk = (const float*)d_in[5];
  const float* Wv = (const float*)d_in[6];
  const float* bv = (const float*)d_in[7];
  const float* Wo = (const float*)d_in[8];
  const float* bo = (const float*)d_in[9];
  float* out = (float*)d_out;

  ushort* xb  = (ushort*)d_ws;                    // [N,E] bf16
  ushort* wqb = xb + (size_t)N_ * E_;             // [E,E] bf16
  ushort* wkb = wqb + (size_t)E_ * E_;
  ushort* wvb = wkb + (size_t)E_ * E_;
  ushort* wob = wvb + (size_t)E_ * E_;
  ushort* rmb = wob + (size_t)E_ * E_;            // [H,P,D] bf16
  ushort* qb  = rmb + (size_t)H_ * P_ * D_;       // [N,E] bf16
  ushort* kb  = qb + (size_t)N_ * E_;             // [N,E] bf16
  ushort* vb  = kb + (size_t)N_ * E_;             // [N,E] bf16
  ushort* pqb = vb + (size_t)N_ * E_;             // [N,H,K2] bf16
  ushort* pkb = pqb + (size_t)N_ * H_ * K2;       // [N,H,K2] bf16
  ushort* attnb = pkb + (size_t)N_ * H_ * K2;     // [N,E] bf16
  ushort* cS = attnb + (size_t)N_ * E_;           // [NC,BH,K2,D] bf16 (8 MB)
  float* cz = (float*)(cS + (size_t)NC * BH * K2 * D_);  // [NC,BH,K2] f32

  cast_kernel<<<dim3(512, 6), dim3(256), 0, stream>>>(
      x, Wq, Wk, Wv, Wo, rm, xb, wqb, wkb, wvb, wob, rmb);
  gemm_qkv_kernel<<<dim3(N_ / 128, E_ / 64, 3), dim3(256), 0, stream>>>(
      xb, wqb, wkb, wvb, bq, bk, bv, qb, kb, vb);
  phi_kernel<<<dim3(N_ / 64, H_, 2), dim3(256), 0, stream>>>(qb, kb, rmb, pqb, pkb);
  chunk_sum_kernel<<<dim3(NC, BH), dim3(256), 0, stream>>>(pkb, vb, cS, cz);
  prefix_kernel<<<dim3(1024), dim3(256), 0, stream>>>(cS, cz);
  chunk_out_kernel<<<dim3(NC, BH), dim3(256), 0, stream>>>(pqb, pkb, vb, cS, cz, attnb);
  gemm_out_kernel<<<dim3(N_ / 128, E_ / 64), dim3(256), 0, stream>>>(attnb, wob, bo, out);
}

// Round 13
// 60.442 us; speedup vs baseline: 3.2892x; 1.0358x over previous
//
#include <hip/hip_runtime.h>

#define T_ 1024
#define B_ 4
#define E_ 512
#define H_ 8
#define D_ 64
#define P_ 64
#define K2 128            // 2P
#define N_ (T_*B_)        // 4096 rows (t*B + b)
#define CHK 64            // scan chunk length
#define NC (T_/CHK)       // 16 chunks
#define BH (B_*H_)        // 32
#define EPSV 1e-6f

typedef unsigned int uint;
typedef unsigned short ushort;
typedef short short8 __attribute__((ext_vector_type(8)));   // 8 bf16 (MFMA A/B frag)
typedef float f32x4 __attribute__((ext_vector_type(4)));    // MFMA C/D frag

__device__ __forceinline__ float b2f(ushort u){ return __uint_as_float(((uint)u) << 16); }
__device__ __forceinline__ ushort f2b(float f){
  uint x = __float_as_uint(f);
  return (ushort)((x + 0x7fffu + ((x >> 16) & 1u)) >> 16);   // RNE
}
__device__ __forceinline__ float lo16(uint u){ return __uint_as_float(u << 16); }
__device__ __forceinline__ float hi16(uint u){ return __uint_as_float(u & 0xffff0000u); }
__device__ __forceinline__ void st(float* p, float v){ *p = v; }
__device__ __forceinline__ void st(ushort* p, float v){ *p = f2b(v); }

// async global->LDS, 16B per lane; LDS dest = wave-uniform base + lane*16 (m104)
__device__ __forceinline__ void gl16(const ushort* g, ushort* lds) {
  __builtin_amdgcn_global_load_lds(
      (const __attribute__((address_space(1))) uint*)g,
      (__attribute__((address_space(3))) uint*)lds, 16, 0, 0);
}

// ---------------- cast f32 -> bf16 (x + 4 weights + rm) ----------------
__global__ __launch_bounds__(256) void cast_kernel(
    const float* __restrict__ x, const float* __restrict__ wq, const float* __restrict__ wk,
    const float* __restrict__ wv, const float* __restrict__ wo, const float* __restrict__ rm,
    ushort* __restrict__ xb, ushort* __restrict__ wqb, ushort* __restrict__ wkb,
    ushort* __restrict__ wvb, ushort* __restrict__ wob, ushort* __restrict__ rmb)
{
  const float* src; ushort* dst; int n4;
  switch (blockIdx.y) {
    case 0:  src = x;  dst = xb;  n4 = N_ * E_ / 4; break;
    case 1:  src = wq; dst = wqb; n4 = E_ * E_ / 4; break;
    case 2:  src = wk; dst = wkb; n4 = E_ * E_ / 4; break;
    case 3:  src = wv; dst = wvb; n4 = E_ * E_ / 4; break;
    case 4:  src = wo; dst = wob; n4 = E_ * E_ / 4; break;
    default: src = rm; dst = rmb; n4 = H_ * P_ * D_ / 4; break;
  }
  const int stride = gridDim.x * 256;
  for (int i = blockIdx.x * 256 + threadIdx.x; i < n4; i += stride) {
    const float4 v = *(const float4*)(src + (size_t)i * 4);
    ushort4 o; o.x = f2b(v.x); o.y = f2b(v.y); o.z = f2b(v.z); o.w = f2b(v.w);
    *(ushort4*)(dst + (size_t)i * 4) = o;
  }
}

// ---------------- LDS-staged MFMA GEMM tile: 128x64, BK=32, FOUR waves ----------------
template<typename OutT>
__device__ __forceinline__ void gemm_tile(
    const ushort* __restrict__ A, const ushort* __restrict__ W,
    const float* __restrict__ bias, OutT* __restrict__ out,
    const int row0, const int col0)
{
  __shared__ ushort sA[128 * 32];   // [row][32] rows of 64B, linear
  __shared__ ushort sB[64 * 32];
  const int tid = threadIdx.x, w = tid >> 6, lane = tid & 63;
  const int lrow = lane >> 2, lk8 = (lane & 3) * 8;   // 16 rows per 1KB issue
  const ushort* gA = A + (size_t)(row0 + w * 32 + lrow) * E_ + lk8;
  const ushort* gB = W + (size_t)(col0 + w * 16 + lrow) * E_ + lk8;
  ushort* lA = sA + w * 1024;       // wave w's 32 A-rows
  ushort* lB = sB + w * 512;        // wave w's 16 B-rows
  const int r = lane & 15, kg = lane >> 4, kq = kg * 8;
  f32x4 acc[2][4] = {};
  for (int k0 = 0; k0 < E_; k0 += 32) {
    gl16(gA + k0,           lA);
    gl16(gA + k0 + 16 * E_, lA + 512);
    gl16(gB + k0,           lB);
    __syncthreads();
    short8 af[2], bf[4];
    #pragma unroll
    for (int m = 0; m < 2; ++m) af[m] = *(const short8*)(sA + (w * 32 + m * 16 + r) * 32 + kq);
    #pragma unroll
    for (int n = 0; n < 4; ++n) bf[n] = *(const short8*)(sB + (n * 16 + r) * 32 + kq);
    #pragma unroll
    for (int m = 0; m < 2; ++m)
      #pragma unroll
      for (int n = 0; n < 4; ++n)
        acc[m][n] = __builtin_amdgcn_mfma_f32_16x16x32_bf16(af[m], bf[n], acc[m][n], 0, 0, 0);
    __syncthreads();
  }
  float bs[4];
  #pragma unroll
  for (int n = 0; n < 4; ++n) bs[n] = bias[col0 + n * 16 + r];
  #pragma unroll
  for (int m = 0; m < 2; ++m) {
    #pragma unroll
    for (int j = 0; j < 4; ++j) {
      const int row_g = row0 + w * 32 + m * 16 + kg * 4 + j;
      #pragma unroll
      for (int n = 0; n < 4; ++n)
        st(out + (size_t)row_g * E_ + col0 + n * 16 + r, acc[m][n][j] + bs[n]);
    }
  }
}

__global__ __launch_bounds__(256) void gemm_qkv_kernel(
    const ushort* __restrict__ A,
    const ushort* __restrict__ wq, const ushort* __restrict__ wk, const ushort* __restrict__ wv,
    const float* __restrict__ bq, const float* __restrict__ bk, const float* __restrict__ bv,
    ushort* __restrict__ qb, ushort* __restrict__ kb, ushort* __restrict__ vb)
{
  const ushort* W; const float* bias; ushort* dst;
  if (blockIdx.z == 0)      { W = wq; bias = bq; dst = qb; }
  else if (blockIdx.z == 1) { W = wk; bias = bk; dst = kb; }
  else                      { W = wv; bias = bv; dst = vb; }
  gemm_tile<ushort>(A, W, bias, dst, blockIdx.x * 128, blockIdx.y * 64);
}

__global__ __launch_bounds__(256) void gemm_out_kernel(
    const ushort* __restrict__ A, const ushort* __restrict__ W,
    const float* __restrict__ bias, float* __restrict__ out)
{
  gemm_tile<float>(A, W, bias, out, blockIdx.x * 128, blockIdx.y * 64);
}

// ---------------- phi via MFMA ----------------
__global__ __launch_bounds__(256) void phi_kernel(
    const ushort* __restrict__ qb, const ushort* __restrict__ kb,
    const ushort* __restrict__ rmb, ushort* __restrict__ pq, ushort* __restrict__ pk)
{
  __shared__ ushort xq[64][72];    // q tile [n][d]
  __shared__ ushort rms[64][72];   // rm[h]  [p][d]
  __shared__ float inv_s[64];
  const int tid = threadIdx.x;
  const int h = blockIdx.y;
  const ushort* src = blockIdx.z ? kb : qb;
  ushort* dst = blockIdx.z ? pk : pq;
  const int n0 = blockIdx.x * 64;
  const int row = tid >> 2, seg = (tid & 3) * 16;
  {
    const ushort* gq = src + (size_t)(n0 + row) * E_ + h * D_ + seg;
    const ushort* gr = rmb + ((size_t)h * P_ + row) * D_ + seg;
    const uint4 q0 = *(const uint4*)(gq);
    const uint4 q1 = *(const uint4*)(gq + 8);
    *(uint4*)(&xq[row][seg])      = q0;
    *(uint4*)(&xq[row][seg + 8])  = q1;
    *(uint4*)(&rms[row][seg])     = *(const uint4*)(gr);
    *(uint4*)(&rms[row][seg + 8]) = *(const uint4*)(gr + 8);
    float s2 = 0.f;
    const uint* qw = (const uint*)&q0;
    #pragma unroll
    for (int i = 0; i < 4; ++i) { const float a = lo16(qw[i]), b = hi16(qw[i]); s2 += a*a + b*b; }
    const uint* qw1 = (const uint*)&q1;
    #pragma unroll
    for (int i = 0; i < 4; ++i) { const float a = lo16(qw1[i]), b = hi16(qw1[i]); s2 += a*a + b*b; }
    s2 += __shfl_xor(s2, 1, 64);
    s2 += __shfl_xor(s2, 2, 64);
    if ((tid & 3) == 0) inv_s[row] = 1.0f / fmaxf(sqrtf(s2), EPSV);
  }
  __syncthreads();
  const int w = tid >> 6, lane = tid & 63;
  const int r = lane & 15, kg = lane >> 4;
  const int m0 = w * 16;
  f32x4 acc[4] = {};
  #pragma unroll
  for (int k0 = 0; k0 < D_; k0 += 32) {
    const short8 a = *(const short8*)(&xq[m0 + r][k0 + kg * 8]);
    #pragma unroll
    for (int nt = 0; nt < 4; ++nt) {
      const short8 bfr = *(const short8*)(&rms[nt * 16 + r][k0 + kg * 8]);
      acc[nt] = __builtin_amdgcn_mfma_f32_16x16x32_bf16(a, bfr, acc[nt], 0, 0, 0);
    }
  }
  #pragma unroll
  for (int j = 0; j < 4; ++j) {
    const int rr = m0 + kg * 4 + j;
    const float inv = inv_s[rr];
    const size_t base = ((size_t)(n0 + rr) * H_ + h) * K2;
    #pragma unroll
    for (int nt = 0; nt < 4; ++nt) {
      const int p = nt * 16 + r;
      const float proj = acc[nt][j] * inv;
      dst[base + p]      = f2b(__sinf(proj) * 0.125f);   // P^-0.5
      dst[base + 64 + p] = f2b(__cosf(proj) * 0.125f);
    }
  }
}

// ---------------- chunk_sum via MFMA (bf16 out; XOR-swizzled transposed staging) ----------------
// Swizzle: col' = col ^ (row & 56). XOR operand is a multiple of 8, so 8-aligned runs stay
// contiguous (b128 frag reads just XOR their base); staging writes spread across banks.
__global__ __launch_bounds__(256) void chunk_sum_kernel(
    const ushort* __restrict__ pk, const ushort* __restrict__ v,
    ushort* __restrict__ cS, float* __restrict__ cz)
{
  const int c = blockIdx.x, bh = blockIdx.y, b = bh >> 3, h = bh & 7;
  __shared__ ushort pkT[K2][88];   // [k2][tau^swz]
  __shared__ ushort vT[D_][88];    // [d][tau^swz]
  const int tid = threadIdx.x;
  for (int i = tid; i < CHK * 16; i += 256) {
    const int tt = i >> 4, k8 = (i & 15) * 8;
    const int n = (c * CHK + tt) * B_ + b;
    const ushort4 u0 = *(const ushort4*)(pk + ((size_t)n * H_ + h) * K2 + k8);
    const ushort4 u1 = *(const ushort4*)(pk + ((size_t)n * H_ + h) * K2 + k8 + 4);
    const int cs = tt ^ (k8 & 56);           // (k8+e)&56 == k8&56 for e<8
    pkT[k8+0][cs] = u0.x; pkT[k8+1][cs] = u0.y; pkT[k8+2][cs] = u0.z; pkT[k8+3][cs] = u0.w;
    pkT[k8+4][cs] = u1.x; pkT[k8+5][cs] = u1.y; pkT[k8+6][cs] = u1.z; pkT[k8+7][cs] = u1.w;
  }
  for (int i = tid; i < CHK * 16; i += 256) {
    const int tt = i >> 4, d4 = (i & 15) * 4;
    const int n = (c * CHK + tt) * B_ + b;
    const ushort4 u = *(const ushort4*)(v + (size_t)n * E_ + h * D_ + d4);
    const int cs = tt ^ (d4 & 56);           // 4-runs never cross an 8-boundary
    vT[d4+0][cs] = u.x; vT[d4+1][cs] = u.y; vT[d4+2][cs] = u.z; vT[d4+3][cs] = u.w;
  }
  __syncthreads();
  const int w = tid >> 6, lane = tid & 63;
  const int r = lane & 15, kb = lane >> 4;
  const int m0 = w * 32;
  f32x4 acc[2][4] = {};
  #pragma unroll
  for (int k0 = 0; k0 < CHK; k0 += 32) {
    const int kqb = k0 + kb * 8;
    const short8 a0 = *(const short8*)(&pkT[m0 + r][kqb ^ ((m0 + r) & 56)]);
    const short8 a1 = *(const short8*)(&pkT[m0 + 16 + r][kqb ^ ((m0 + 16 + r) & 56)]);
    #pragma unroll
    for (int nt = 0; nt < 4; ++nt) {
      const short8 bv = *(const short8*)(&vT[nt * 16 + r][kqb ^ ((nt * 16 + r) & 56)]);
      acc[0][nt] = __builtin_amdgcn_mfma_f32_16x16x32_bf16(a0, bv, acc[0][nt], 0, 0, 0);
      acc[1][nt] = __builtin_amdgcn_mfma_f32_16x16x32_bf16(a1, bv, acc[1][nt], 0, 0, 0);
    }
  }
  ushort* So = cS + (size_t)(c * BH + bh) * (K2 * D_);
  #pragma unroll
  for (int mt = 0; mt < 2; ++mt)
    #pragma unroll
    for (int nt = 0; nt < 4; ++nt)
      #pragma unroll
      for (int j = 0; j < 4; ++j)
        So[(m0 + mt * 16 + kb * 4 + j) * D_ + nt * 16 + r] = f2b(acc[mt][nt][j]);
  if (tid < K2) {
    float zacc = 0.f;
    #pragma unroll
    for (int i2 = 0; i2 < CHK / 2; ++i2) {
      const uint u = *(const uint*)(&pkT[tid][(i2 * 2) ^ (tid & 56)]);  // pair stays adjacent
      zacc += lo16(u) + hi16(u);
    }
    cz[(size_t)(c * BH + bh) * K2 + tid] = zacc;
  }
}

// ---------------- exclusive prefix over chunks (bf16 data, f32 accumulator) ----------------
__global__ __launch_bounds__(256) void prefix_kernel(
    ushort* __restrict__ cS, float* __restrict__ cz)
{
  const int gid = blockIdx.x * 256 + threadIdx.x;   // 262144 threads
  const int bh = gid >> 13, rem = gid & 8191;
  float run = 0.f;
  #pragma unroll
  for (int c = 0; c < NC; ++c) {
    ushort* p = cS + (((size_t)(c * BH + bh)) << 13) + rem;
    const float t = b2f(*p); *p = f2b(run); run += t;
  }
  if (gid < BH * K2) {
    const int zbh = gid >> 7, k2 = gid & 127;
    float rz = 0.f;
    #pragma unroll
    for (int c = 0; c < NC; ++c) {
      float* pz = cz + (size_t)(c * BH + zbh) * K2 + k2;
      const float t = *pz; *pz = rz; rz += t;
    }
  }
}

// ---------------- chunk_out via MFMA (Sp bf16; XOR-swizzled vT_s / SpT_s) ----------------
__global__ __launch_bounds__(256) void chunk_out_kernel(
    const ushort* __restrict__ pq, const ushort* __restrict__ pkg,
    const ushort* __restrict__ v, const ushort* __restrict__ Sp,
    const float* __restrict__ zp, ushort* __restrict__ attn)
{
  const int c = blockIdx.x, bh = blockIdx.y, b = bh >> 3, h = bh & 7;
  __shared__ ushort pq_s[CHK][136];
  __shared__ ushort pk_s[CHK][136];
  __shared__ ushort SpT_s[D_][136];   // [d][k2^swz] bf16
  __shared__ ushort vT_s[D_][88];     // [d][tau^swz]
  __shared__ ushort Am_s[CHK][88];    // masked A bf16 [t][tau] (unswizzled; ~4-way)
  __shared__ float zps[K2];
  __shared__ float dens_s[CHK];
  __shared__ float inv_s[CHK];
  const int tid = threadIdx.x;
  for (int i = tid; i < CHK * 16; i += 256) {
    const int tt = i >> 4, k8 = (i & 15) * 8;
    const int n = (c * CHK + tt) * B_ + b;
    const size_t off = ((size_t)n * H_ + h) * K2 + k8;
    *(uint4*)(&pq_s[tt][k8]) = *(const uint4*)(pq + off);
    *(uint4*)(&pk_s[tt][k8]) = *(const uint4*)(pkg + off);
  }
  for (int i = tid; i < CHK * 16; i += 256) {
    const int tt = i >> 4, d4 = (i & 15) * 4;
    const int n = (c * CHK + tt) * B_ + b;
    const ushort4 u = *(const ushort4*)(v + (size_t)n * E_ + h * D_ + d4);
    const int cs = tt ^ (d4 & 56);
    vT_s[d4+0][cs] = u.x; vT_s[d4+1][cs] = u.y; vT_s[d4+2][cs] = u.z; vT_s[d4+3][cs] = u.w;
  }
  const ushort* Spb = Sp + (size_t)(c * BH + bh) * (K2 * D_);
  for (int i = tid; i < K2 * 8; i += 256) {
    const int k2 = i >> 3, d8 = (i & 7) * 8;
    const ushort4 s0 = *(const ushort4*)(Spb + k2 * D_ + d8);
    const ushort4 s1 = *(const ushort4*)(Spb + k2 * D_ + d8 + 4);
    const int cs = k2 ^ d8;                  // rows d8..d8+7: (d&56)==d8
    SpT_s[d8+0][cs] = s0.x; SpT_s[d8+1][cs] = s0.y;
    SpT_s[d8+2][cs] = s0.z; SpT_s[d8+3][cs] = s0.w;
    SpT_s[d8+4][cs] = s1.x; SpT_s[d8+5][cs] = s1.y;
    SpT_s[d8+6][cs] = s1.z; SpT_s[d8+7][cs] = s1.w;
  }
  if (tid < K2) zps[tid] = zp[(size_t)(c * BH + bh) * K2 + tid];
  __syncthreads();

  const int w = tid >> 6, lane = tid & 63;
  const int r = lane & 15, kb = lane >> 4;
  const int m0 = w * 16;
  f32x4 accA[4] = {};
  #pragma unroll
  for (int k0 = 0; k0 < K2; k0 += 32) {
    const short8 aq = *(const short8*)(&pq_s[m0 + r][k0 + kb * 8]);
    #pragma unroll
    for (int nt = 0; nt < 4; ++nt) {
      const short8 bk = *(const short8*)(&pk_s[nt * 16 + r][k0 + kb * 8]);
      accA[nt] = __builtin_amdgcn_mfma_f32_16x16x32_bf16(aq, bk, accA[nt], 0, 0, 0);
    }
  }
  float rs[4] = {0.f, 0.f, 0.f, 0.f};
  #pragma unroll
  for (int nt = 0; nt < 4; ++nt) {
    #pragma unroll
    for (int j = 0; j < 4; ++j) {
      const int row = kb * 4 + j, col = nt * 16 + r;
      float a = accA[nt][j];
      a = (col <= m0 + row) ? a : 0.f;
      rs[j] += a;
      Am_s[m0 + row][col] = f2b(a);
    }
  }
  #pragma unroll
  for (int off = 1; off < 16; off <<= 1) {
    rs[0] += __shfl_xor(rs[0], off, 64);
    rs[1] += __shfl_xor(rs[1], off, 64);
    rs[2] += __shfl_xor(rs[2], off, 64);
    rs[3] += __shfl_xor(rs[3], off, 64);
  }
  if (r == 0) {
    #pragma unroll
    for (int j = 0; j < 4; ++j) dens_s[m0 + kb * 4 + j] = rs[j];
  }
  f32x4 accO[4] = {};
  #pragma unroll
  for (int k0 = 0; k0 < CHK; k0 += 32) {
    const int kqb = k0 + kb * 8;
    const short8 aa = *(const short8*)(&Am_s[m0 + r][kqb]);
    #pragma unroll
    for (int nt = 0; nt < 4; ++nt) {
      const short8 bv = *(const short8*)(&vT_s[nt * 16 + r][kqb ^ ((nt * 16 + r) & 56)]);
      accO[nt] = __builtin_amdgcn_mfma_f32_16x16x32_bf16(aa, bv, accO[nt], 0, 0, 0);
    }
  }
  #pragma unroll
  for (int k0 = 0; k0 < K2; k0 += 32) {
    const int kqb = k0 + kb * 8;
    const short8 aq = *(const short8*)(&pq_s[m0 + r][kqb]);
    #pragma unroll
    for (int nt = 0; nt < 4; ++nt) {
      const short8 bs = *(const short8*)(&SpT_s[nt * 16 + r][kqb ^ ((nt * 16 + r) & 56)]);
      accO[nt] = __builtin_amdgcn_mfma_f32_16x16x32_bf16(aq, bs, accO[nt], 0, 0, 0);
    }
  }
  {
    const int t_loc = m0 + (lane >> 2), seg = lane & 3;
    float qz = 0.f;
    #pragma unroll
    for (int ii = 0; ii < 16; ++ii) {
      const uint u = *(const uint*)(&pq_s[t_loc][seg * 32 + ii * 2]);
      qz += lo16(u) * zps[seg * 32 + ii * 2] + hi16(u) * zps[seg * 32 + ii * 2 + 1];
    }
    qz += __shfl_xor(qz, 1, 64);
    qz += __shfl_xor(qz, 2, 64);
    if (seg == 0) inv_s[t_loc] = 1.0f / fmaxf(dens_s[t_loc] + qz, EPSV);
  }
  #pragma unroll
  for (int j = 0; j < 4; ++j) {
    const int row = m0 + kb * 4 + j;
    const float inv = inv_s[row];
    const int n = (c * CHK + row) * B_ + b;
    ushort* op = attn + (size_t)n * E_ + h * D_;
    #pragma unroll
    for (int nt = 0; nt < 4; ++nt) op[nt * 16 + r] = f2b(accO[nt][j] * inv);
  }
}

extern "C" void kernel_launch(void* const* d_in, const int* in_sizes, int n_in,
                              void* d_out, int out_size, void* d_ws, size_t ws_size,
                              hipStream_t stream) {
  const float* x  = (const float*)d_in[0];
  const float* rm = (const float*)d_in[1];
  const float* Wq = (const float*)d_in[2];
  const float* bq = (const float*)d_in[3];
  const float* Wk = (const float*)d_in[4];
  const float* bk = (const float*)d_in[5];
  const float* Wv = (const float*)d_in[6];
  const float* bv = (const float*)d_in[7];
  const float* Wo = (const float*)d_in[8];
  const float* bo = (const float*)d_in[9];
  float* out = (float*)d_out;

  ushort* xb  = (ushort*)d_ws;                    // [N,E] bf16
  ushort* wqb = xb + (size_t)N_ * E_;             // [E,E] bf16
  ushort* wkb = wqb + (size_t)E_ * E_;
  ushort* wvb = wkb + (size_t)E_ * E_;
  ushort* wob = wvb + (size_t)E_ * E_;
  ushort* rmb = wob + (size_t)E_ * E_;            // [H,P,D] bf16
  ushort* qb  = rmb + (size_t)H_ * P_ * D_;       // [N,E] bf16
  ushort* kb  = qb + (size_t)N_ * E_;             // [N,E] bf16
  ushort* vb  = kb + (size_t)N_ * E_;             // [N,E] bf16
  ushort* pqb = vb + (size_t)N_ * E_;             // [N,H,K2] bf16
  ushort* pkb = pqb + (size_t)N_ * H_ * K2;       // [N,H,K2] bf16
  ushort* attnb = pkb + (size_t)N_ * H_ * K2;     // [N,E] bf16
  ushort* cS = attnb + (size_t)N_ * E_;           // [NC,BH,K2,D] bf16 (8 MB)
  float* cz = (float*)(cS + (size_t)NC * BH * K2 * D_);  // [NC,BH,K2] f32

  cast_kernel<<<dim3(512, 6), dim3(256), 0, stream>>>(
      x, Wq, Wk, Wv, Wo, rm, xb, wqb, wkb, wvb, wob, rmb);
  gemm_qkv_kernel<<<dim3(N_ / 128, E_ / 64, 3), dim3(256), 0, stream>>>(
      xb, wqb, wkb, wvb, bq, bk, bv, qb, kb, vb);
  phi_kernel<<<dim3(N_ / 64, H_, 2), dim3(256), 0, stream>>>(qb, kb, rmb, pqb, pkb);
  chunk_sum_kernel<<<dim3(NC, BH), dim3(256), 0, stream>>>(pkb, vb, cS, cz);
  prefix_kernel<<<dim3(1024), dim3(256), 0, stream>>>(cS, cz);
  chunk_out_kernel<<<dim3(NC, BH), dim3(256), 0, stream>>>(pqb, pkb, vb, cS, cz, attnb);
  gemm_out_kernel<<<dim3(N_ / 128, E_ / 64), dim3(256), 0, stream>>>(attnb, wob, bo, out);
}

// Round 16
// 60.220 us; speedup vs baseline: 3.3013x; 1.0037x over previous
//
#include <hip/hip_runtime.h>

#define T_ 1024
#define B_ 4
#define E_ 512
#define H_ 8
#define D_ 64
#define P_ 64
#define K2 128            // 2P
#define N_ (T_*B_)        // 4096 rows (t*B + b)
#define CHK 64            // scan chunk length
#define NC (T_/CHK)       // 16 chunks
#define BH (B_*H_)        // 32
#define EPSV 1e-6f

typedef unsigned int uint;
typedef unsigned short ushort;
typedef short short8 __attribute__((ext_vector_type(8)));   // 8 bf16 (MFMA A/B frag)
typedef float f32x4 __attribute__((ext_vector_type(4)));    // MFMA C/D frag

__device__ __forceinline__ float b2f(ushort u){ return __uint_as_float(((uint)u) << 16); }
__device__ __forceinline__ ushort f2b(float f){
  uint x = __float_as_uint(f);
  return (ushort)((x + 0x7fffu + ((x >> 16) & 1u)) >> 16);   // RNE
}
__device__ __forceinline__ float lo16(uint u){ return __uint_as_float(u << 16); }
__device__ __forceinline__ float hi16(uint u){ return __uint_as_float(u & 0xffff0000u); }
__device__ __forceinline__ void st(float* p, float v){ *p = v; }
__device__ __forceinline__ void st(ushort* p, float v){ *p = f2b(v); }

// async global->LDS, 16B per lane; LDS dest = wave-uniform base + lane*16 (m104)
__device__ __forceinline__ void gl16(const ushort* g, ushort* lds) {
  __builtin_amdgcn_global_load_lds(
      (const __attribute__((address_space(1))) uint*)g,
      (__attribute__((address_space(3))) uint*)lds, 16, 0, 0);
}

// ---------------- cast f32 -> bf16 (x + 4 weights + rm) ----------------
__global__ __launch_bounds__(256) void cast_kernel(
    const float* __restrict__ x, const float* __restrict__ wq, const float* __restrict__ wk,
    const float* __restrict__ wv, const float* __restrict__ wo, const float* __restrict__ rm,
    ushort* __restrict__ xb, ushort* __restrict__ wqb, ushort* __restrict__ wkb,
    ushort* __restrict__ wvb, ushort* __restrict__ wob, ushort* __restrict__ rmb)
{
  const float* src; ushort* dst; int n4;
  switch (blockIdx.y) {
    case 0:  src = x;  dst = xb;  n4 = N_ * E_ / 4; break;
    case 1:  src = wq; dst = wqb; n4 = E_ * E_ / 4; break;
    case 2:  src = wk; dst = wkb; n4 = E_ * E_ / 4; break;
    case 3:  src = wv; dst = wvb; n4 = E_ * E_ / 4; break;
    case 4:  src = wo; dst = wob; n4 = E_ * E_ / 4; break;
    default: src = rm; dst = rmb; n4 = H_ * P_ * D_ / 4; break;
  }
  const int stride = gridDim.x * 256;
  for (int i = blockIdx.x * 256 + threadIdx.x; i < n4; i += stride) {
    const float4 v = *(const float4*)(src + (size_t)i * 4);
    ushort4 o; o.x = f2b(v.x); o.y = f2b(v.y); o.z = f2b(v.z); o.w = f2b(v.w);
    *(ushort4*)(dst + (size_t)i * 4) = o;
  }
}

// ---------------- LDS-staged MFMA GEMM tile: 128x64, BK=32, FOUR waves ----------------
template<typename OutT>
__device__ __forceinline__ void gemm_tile(
    const ushort* __restrict__ A, const ushort* __restrict__ W,
    const float* __restrict__ bias, OutT* __restrict__ out,
    const int row0, const int col0)
{
  __shared__ ushort sA[128 * 32];   // [row][32] rows of 64B, linear
  __shared__ ushort sB[64 * 32];
  const int tid = threadIdx.x, w = tid >> 6, lane = tid & 63;
  const int lrow = lane >> 2, lk8 = (lane & 3) * 8;   // 16 rows per 1KB issue
  const ushort* gA = A + (size_t)(row0 + w * 32 + lrow) * E_ + lk8;
  const ushort* gB = W + (size_t)(col0 + w * 16 + lrow) * E_ + lk8;
  ushort* lA = sA + w * 1024;       // wave w's 32 A-rows
  ushort* lB = sB + w * 512;        // wave w's 16 B-rows
  const int r = lane & 15, kg = lane >> 4, kq = kg * 8;
  f32x4 acc[2][4] = {};
  for (int k0 = 0; k0 < E_; k0 += 32) {
    gl16(gA + k0,           lA);
    gl16(gA + k0 + 16 * E_, lA + 512);
    gl16(gB + k0,           lB);
    __syncthreads();
    short8 af[2], bf[4];
    #pragma unroll
    for (int m = 0; m < 2; ++m) af[m] = *(const short8*)(sA + (w * 32 + m * 16 + r) * 32 + kq);
    #pragma unroll
    for (int n = 0; n < 4; ++n) bf[n] = *(const short8*)(sB + (n * 16 + r) * 32 + kq);
    #pragma unroll
    for (int m = 0; m < 2; ++m)
      #pragma unroll
      for (int n = 0; n < 4; ++n)
        acc[m][n] = __builtin_amdgcn_mfma_f32_16x16x32_bf16(af[m], bf[n], acc[m][n], 0, 0, 0);
    __syncthreads();
  }
  float bs[4];
  #pragma unroll
  for (int n = 0; n < 4; ++n) bs[n] = bias[col0 + n * 16 + r];
  #pragma unroll
  for (int m = 0; m < 2; ++m) {
    #pragma unroll
    for (int j = 0; j < 4; ++j) {
      const int row_g = row0 + w * 32 + m * 16 + kg * 4 + j;
      #pragma unroll
      for (int n = 0; n < 4; ++n)
        st(out + (size_t)row_g * E_ + col0 + n * 16 + r, acc[m][n][j] + bs[n]);
    }
  }
}

__global__ __launch_bounds__(256) void gemm_qkv_kernel(
    const ushort* __restrict__ A,
    const ushort* __restrict__ wq, const ushort* __restrict__ wk, const ushort* __restrict__ wv,
    const float* __restrict__ bq, const float* __restrict__ bk, const float* __restrict__ bv,
    ushort* __restrict__ qb, ushort* __restrict__ kb, ushort* __restrict__ vb)
{
  const ushort* W; const float* bias; ushort* dst;
  if (blockIdx.z == 0)      { W = wq; bias = bq; dst = qb; }
  else if (blockIdx.z == 1) { W = wk; bias = bk; dst = kb; }
  else                      { W = wv; bias = bv; dst = vb; }
  gemm_tile<ushort>(A, W, bias, dst, blockIdx.x * 128, blockIdx.y * 64);
}

__global__ __launch_bounds__(256) void gemm_out_kernel(
    const ushort* __restrict__ A, const ushort* __restrict__ W,
    const float* __restrict__ bias, float* __restrict__ out)
{
  gemm_tile<float>(A, W, bias, out, blockIdx.x * 128, blockIdx.y * 64);
}

// ---------------- phi via MFMA ----------------
__global__ __launch_bounds__(256) void phi_kernel(
    const ushort* __restrict__ qb, const ushort* __restrict__ kb,
    const ushort* __restrict__ rmb, ushort* __restrict__ pq, ushort* __restrict__ pk)
{
  __shared__ ushort xq[64][72];    // q tile [n][d]
  __shared__ ushort rms[64][72];   // rm[h]  [p][d]
  __shared__ float inv_s[64];
  const int tid = threadIdx.x;
  const int h = blockIdx.y;
  const ushort* src = blockIdx.z ? kb : qb;
  ushort* dst = blockIdx.z ? pk : pq;
  const int n0 = blockIdx.x * 64;
  const int row = tid >> 2, seg = (tid & 3) * 16;
  {
    const ushort* gq = src + (size_t)(n0 + row) * E_ + h * D_ + seg;
    const ushort* gr = rmb + ((size_t)h * P_ + row) * D_ + seg;
    const uint4 q0 = *(const uint4*)(gq);
    const uint4 q1 = *(const uint4*)(gq + 8);
    *(uint4*)(&xq[row][seg])      = q0;
    *(uint4*)(&xq[row][seg + 8])  = q1;
    *(uint4*)(&rms[row][seg])     = *(const uint4*)(gr);
    *(uint4*)(&rms[row][seg + 8]) = *(const uint4*)(gr + 8);
    float s2 = 0.f;
    const uint* qw = (const uint*)&q0;
    #pragma unroll
    for (int i = 0; i < 4; ++i) { const float a = lo16(qw[i]), b = hi16(qw[i]); s2 += a*a + b*b; }
    const uint* qw1 = (const uint*)&q1;
    #pragma unroll
    for (int i = 0; i < 4; ++i) { const float a = lo16(qw1[i]), b = hi16(qw1[i]); s2 += a*a + b*b; }
    s2 += __shfl_xor(s2, 1, 64);
    s2 += __shfl_xor(s2, 2, 64);
    if ((tid & 3) == 0) inv_s[row] = 1.0f / fmaxf(sqrtf(s2), EPSV);
  }
  __syncthreads();
  const int w = tid >> 6, lane = tid & 63;
  const int r = lane & 15, kg = lane >> 4;
  const int m0 = w * 16;
  f32x4 acc[4] = {};
  #pragma unroll
  for (int k0 = 0; k0 < D_; k0 += 32) {
    const short8 a = *(const short8*)(&xq[m0 + r][k0 + kg * 8]);
    #pragma unroll
    for (int nt = 0; nt < 4; ++nt) {
      const short8 bfr = *(const short8*)(&rms[nt * 16 + r][k0 + kg * 8]);
      acc[nt] = __builtin_amdgcn_mfma_f32_16x16x32_bf16(a, bfr, acc[nt], 0, 0, 0);
    }
  }
  #pragma unroll
  for (int j = 0; j < 4; ++j) {
    const int rr = m0 + kg * 4 + j;
    const float inv = inv_s[rr];
    const size_t base = ((size_t)(n0 + rr) * H_ + h) * K2;
    #pragma unroll
    for (int nt = 0; nt < 4; ++nt) {
      const int p = nt * 16 + r;
      const float proj = acc[nt][j] * inv;
      dst[base + p]      = f2b(__sinf(proj) * 0.125f);   // P^-0.5
      dst[base + 64 + p] = f2b(__cosf(proj) * 0.125f);
    }
  }
}

// ---------------- chunk_sum via MFMA (bf16 out; XOR-swizzled transposed staging) ----------------
__global__ __launch_bounds__(256) void chunk_sum_kernel(
    const ushort* __restrict__ pk, const ushort* __restrict__ v,
    ushort* __restrict__ cS, float* __restrict__ cz)
{
  const int c = blockIdx.x, bh = blockIdx.y, b = bh >> 3, h = bh & 7;
  __shared__ ushort pkT[K2][88];   // [k2][tau^swz]
  __shared__ ushort vT[D_][88];    // [d][tau^swz]
  const int tid = threadIdx.x;
  for (int i = tid; i < CHK * 16; i += 256) {
    const int tt = i >> 4, k8 = (i & 15) * 8;
    const int n = (c * CHK + tt) * B_ + b;
    const ushort4 u0 = *(const ushort4*)(pk + ((size_t)n * H_ + h) * K2 + k8);
    const ushort4 u1 = *(const ushort4*)(pk + ((size_t)n * H_ + h) * K2 + k8 + 4);
    const int cs = tt ^ (k8 & 56);
    pkT[k8+0][cs] = u0.x; pkT[k8+1][cs] = u0.y; pkT[k8+2][cs] = u0.z; pkT[k8+3][cs] = u0.w;
    pkT[k8+4][cs] = u1.x; pkT[k8+5][cs] = u1.y; pkT[k8+6][cs] = u1.z; pkT[k8+7][cs] = u1.w;
  }
  for (int i = tid; i < CHK * 16; i += 256) {
    const int tt = i >> 4, d4 = (i & 15) * 4;
    const int n = (c * CHK + tt) * B_ + b;
    const ushort4 u = *(const ushort4*)(v + (size_t)n * E_ + h * D_ + d4);
    const int cs = tt ^ (d4 & 56);
    vT[d4+0][cs] = u.x; vT[d4+1][cs] = u.y; vT[d4+2][cs] = u.z; vT[d4+3][cs] = u.w;
  }
  __syncthreads();
  const int w = tid >> 6, lane = tid & 63;
  const int r = lane & 15, kb = lane >> 4;
  const int m0 = w * 32;
  f32x4 acc[2][4] = {};
  #pragma unroll
  for (int k0 = 0; k0 < CHK; k0 += 32) {
    const int kqb = k0 + kb * 8;
    const short8 a0 = *(const short8*)(&pkT[m0 + r][kqb ^ ((m0 + r) & 56)]);
    const short8 a1 = *(const short8*)(&pkT[m0 + 16 + r][kqb ^ ((m0 + 16 + r) & 56)]);
    #pragma unroll
    for (int nt = 0; nt < 4; ++nt) {
      const short8 bv = *(const short8*)(&vT[nt * 16 + r][kqb ^ ((nt * 16 + r) & 56)]);
      acc[0][nt] = __builtin_amdgcn_mfma_f32_16x16x32_bf16(a0, bv, acc[0][nt], 0, 0, 0);
      acc[1][nt] = __builtin_amdgcn_mfma_f32_16x16x32_bf16(a1, bv, acc[1][nt], 0, 0, 0);
    }
  }
  ushort* So = cS + (size_t)(c * BH + bh) * (K2 * D_);
  #pragma unroll
  for (int mt = 0; mt < 2; ++mt)
    #pragma unroll
    for (int nt = 0; nt < 4; ++nt)
      #pragma unroll
      for (int j = 0; j < 4; ++j)
        So[(m0 + mt * 16 + kb * 4 + j) * D_ + nt * 16 + r] = f2b(acc[mt][nt][j]);
  if (tid < K2) {
    float zacc = 0.f;
    #pragma unroll
    for (int i2 = 0; i2 < CHK / 2; ++i2) {
      const uint u = *(const uint*)(&pkT[tid][(i2 * 2) ^ (tid & 56)]);
      zacc += lo16(u) + hi16(u);
    }
    cz[(size_t)(c * BH + bh) * K2 + tid] = zacc;
  }
}

// ---------------- exclusive prefix over chunks (bf16 data, f32 accumulator) ----------------
__global__ __launch_bounds__(256) void prefix_kernel(
    ushort* __restrict__ cS, float* __restrict__ cz)
{
  const int gid = blockIdx.x * 256 + threadIdx.x;   // 262144 threads
  const int bh = gid >> 13, rem = gid & 8191;
  float run = 0.f;
  #pragma unroll
  for (int c = 0; c < NC; ++c) {
    ushort* p = cS + (((size_t)(c * BH + bh)) << 13) + rem;
    const float t = b2f(*p); *p = f2b(run); run += t;
  }
  if (gid < BH * K2) {
    const int zbh = gid >> 7, k2 = gid & 127;
    float rz = 0.f;
    #pragma unroll
    for (int c = 0; c < NC; ++c) {
      float* pz = cz + (size_t)(c * BH + zbh) * K2 + k2;
      const float t = *pz; *pz = rz; rz += t;
    }
  }
}

// ---------------- chunk_out via MFMA (Sp bf16; XOR-swizzled vT_s / SpT_s) ----------------
__global__ __launch_bounds__(256) void chunk_out_kernel(
    const ushort* __restrict__ pq, const ushort* __restrict__ pkg,
    const ushort* __restrict__ v, const ushort* __restrict__ Sp,
    const float* __restrict__ zp, ushort* __restrict__ attn)
{
  const int c = blockIdx.x, bh = blockIdx.y, b = bh >> 3, h = bh & 7;
  __shared__ ushort pq_s[CHK][136];
  __shared__ ushort pk_s[CHK][136];
  __shared__ ushort SpT_s[D_][136];   // [d][k2^swz] bf16
  __shared__ ushort vT_s[D_][88];     // [d][tau^swz]
  __shared__ ushort Am_s[CHK][88];    // masked A bf16 [t][tau] (unswizzled; ~4-way)
  __shared__ float zps[K2];
  __shared__ float dens_s[CHK];
  __shared__ float inv_s[CHK];
  const int tid = threadIdx.x;
  for (int i = tid; i < CHK * 16; i += 256) {
    const int tt = i >> 4, k8 = (i & 15) * 8;
    const int n = (c * CHK + tt) * B_ + b;
    const size_t off = ((size_t)n * H_ + h) * K2 + k8;
    *(uint4*)(&pq_s[tt][k8]) = *(const uint4*)(pq + off);
    *(uint4*)(&pk_s[tt][k8]) = *(const uint4*)(pkg + off);
  }
  for (int i = tid; i < CHK * 16; i += 256) {
    const int tt = i >> 4, d4 = (i & 15) * 4;
    const int n = (c * CHK + tt) * B_ + b;
    const ushort4 u = *(const ushort4*)(v + (size_t)n * E_ + h * D_ + d4);
    const int cs = tt ^ (d4 & 56);
    vT_s[d4+0][cs] = u.x; vT_s[d4+1][cs] = u.y; vT_s[d4+2][cs] = u.z; vT_s[d4+3][cs] = u.w;
  }
  const ushort* Spb = Sp + (size_t)(c * BH + bh) * (K2 * D_);
  for (int i = tid; i < K2 * 8; i += 256) {
    const int k2 = i >> 3, d8 = (i & 7) * 8;
    const ushort4 s0 = *(const ushort4*)(Spb + k2 * D_ + d8);
    const ushort4 s1 = *(const ushort4*)(Spb + k2 * D_ + d8 + 4);
    const int cs = k2 ^ d8;
    SpT_s[d8+0][cs] = s0.x; SpT_s[d8+1][cs] = s0.y;
    SpT_s[d8+2][cs] = s0.z; SpT_s[d8+3][cs] = s0.w;
    SpT_s[d8+4][cs] = s1.x; SpT_s[d8+5][cs] = s1.y;
    SpT_s[d8+6][cs] = s1.z; SpT_s[d8+7][cs] = s1.w;
  }
  if (tid < K2) zps[tid] = zp[(size_t)(c * BH + bh) * K2 + tid];
  __syncthreads();

  const int w = tid >> 6, lane = tid & 63;
  const int r = lane & 15, kb = lane >> 4;
  const int m0 = w * 16;
  f32x4 accA[4] = {};
  #pragma unroll
  for (int k0 = 0; k0 < K2; k0 += 32) {
    const short8 aq = *(const short8*)(&pq_s[m0 + r][k0 + kb * 8]);
    #pragma unroll
    for (int nt = 0; nt < 4; ++nt) {
      const short8 bk = *(const short8*)(&pk_s[nt * 16 + r][k0 + kb * 8]);
      accA[nt] = __builtin_amdgcn_mfma_f32_16x16x32_bf16(aq, bk, accA[nt], 0, 0, 0);
    }
  }
  float rs[4] = {0.f, 0.f, 0.f, 0.f};
  #pragma unroll
  for (int nt = 0; nt < 4; ++nt) {
    #pragma unroll
    for (int j = 0; j < 4; ++j) {
      const int row = kb * 4 + j, col = nt * 16 + r;
      float a = accA[nt][j];
      a = (col <= m0 + row) ? a : 0.f;
      rs[j] += a;
      Am_s[m0 + row][col] = f2b(a);
    }
  }
  #pragma unroll
  for (int off = 1; off < 16; off <<= 1) {
    rs[0] += __shfl_xor(rs[0], off, 64);
    rs[1] += __shfl_xor(rs[1], off, 64);
    rs[2] += __shfl_xor(rs[2], off, 64);
    rs[3] += __shfl_xor(rs[3], off, 64);
  }
  if (r == 0) {
    #pragma unroll
    for (int j = 0; j < 4; ++j) dens_s[m0 + kb * 4 + j] = rs[j];
  }
  f32x4 accO[4] = {};
  #pragma unroll
  for (int k0 = 0; k0 < CHK; k0 += 32) {
    const int kqb = k0 + kb * 8;
    const short8 aa = *(const short8*)(&Am_s[m0 + r][kqb]);
    #pragma unroll
    for (int nt = 0; nt < 4; ++nt) {
      const short8 bv = *(const short8*)(&vT_s[nt * 16 + r][kqb ^ ((nt * 16 + r) & 56)]);
      accO[nt] = __builtin_amdgcn_mfma_f32_16x16x32_bf16(aa, bv, accO[nt], 0, 0, 0);
    }
  }
  #pragma unroll
  for (int k0 = 0; k0 < K2; k0 += 32) {
    const int kqb = k0 + kb * 8;
    const short8 aq = *(const short8*)(&pq_s[m0 + r][kqb]);
    #pragma unroll
    for (int nt = 0; nt < 4; ++nt) {
      const short8 bs = *(const short8*)(&SpT_s[nt * 16 + r][kqb ^ ((nt * 16 + r) & 56)]);
      accO[nt] = __builtin_amdgcn_mfma_f32_16x16x32_bf16(aq, bs, accO[nt], 0, 0, 0);
    }
  }
  {
    const int t_loc = m0 + (lane >> 2), seg = lane & 3;
    float qz = 0.f;
    #pragma unroll
    for (int ii = 0; ii < 16; ++ii) {
      const uint u = *(const uint*)(&pq_s[t_loc][seg * 32 + ii * 2]);
      qz += lo16(u) * zps[seg * 32 + ii * 2] + hi16(u) * zps[seg * 32 + ii * 2 + 1];
    }
    qz += __shfl_xor(qz, 1, 64);
    qz += __shfl_xor(qz, 2, 64);
    if (seg == 0) inv_s[t_loc] = 1.0f / fmaxf(dens_s[t_loc] + qz, EPSV);
  }
  #pragma unroll
  for (int j = 0; j < 4; ++j) {
    const int row = m0 + kb * 4 + j;
    const float inv = inv_s[row];
    const int n = (c * CHK + row) * B_ + b;
    ushort* op = attn + (size_t)n * E_ + h * D_;
    #pragma unroll
    for (int nt = 0; nt < 4; ++nt) op[nt * 16 + r] = f2b(accO[nt][j] * inv);
  }
}

extern "C" void kernel_launch(void* const* d_in, const int* in_sizes, int n_in,
                              void* d_out, int out_size, void* d_ws, size_t ws_size,
                              hipStream_t stream) {
  const float* x  = (const float*)d_in[0];
  const float* rm = (const float*)d_in[1];
  const float* Wq = (const float*)d_in[2];
  const float* bq = (const float*)d_in[3];
  const float* Wk = (const float*)d_in[4];
  const float* bk = (const float*)d_in[5];
  const float* Wv = (const float*)d_in[6];
  const float* bv = (const float*)d_in[7];
  const float* Wo = (const float*)d_in[8];
  const float* bo = (const float*)d_in[9];
  float* out = (float*)d_out;

  ushort* xb  = (ushort*)d_ws;                    // [N,E] bf16
  ushort* wqb = xb + (size_t)N_ * E_;             // [E,E] bf16
  ushort* wkb = wqb + (size_t)E_ * E_;
  ushort* wvb = wkb + (size_t)E_ * E_;
  ushort* wob = wvb + (size_t)E_ * E_;
  ushort* rmb = wob + (size_t)E_ * E_;            // [H,P,D] bf16
  ushort* qb  = rmb + (size_t)H_ * P_ * D_;       // [N,E] bf16
  ushort* kb  = qb + (size_t)N_ * E_;             // [N,E] bf16
  ushort* vb  = kb + (size_t)N_ * E_;             // [N,E] bf16
  ushort* pqb = vb + (size_t)N_ * E_;             // [N,H,K2] bf16
  ushort* pkb = pqb + (size_t)N_ * H_ * K2;       // [N,H,K2] bf16
  ushort* attnb = pkb + (size_t)N_ * H_ * K2;     // [N,E] bf16
  ushort* cS = attnb + (size_t)N_ * E_;           // [NC,BH,K2,D] bf16 (8 MB)
  float* cz = (float*)(cS + (size_t)NC * BH * K2 * D_);  // [NC,BH,K2] f32

  cast_kernel<<<dim3(512, 6), dim3(256), 0, stream>>>(
      x, Wq, Wk, Wv, Wo, rm, xb, wqb, wkb, wvb, wob, rmb);
  gemm_qkv_kernel<<<dim3(N_ / 128, E_ / 64, 3), dim3(256), 0, stream>>>(
      xb, wqb, wkb, wvb, bq, bk, bv, qb, kb, vb);
  phi_kernel<<<dim3(N_ / 64, H_, 2), dim3(256), 0, stream>>>(qb, kb, rmb, pqb, pkb);
  chunk_sum_kernel<<<dim3(NC, BH), dim3(256), 0, stream>>>(pkb, vb, cS, cz);
  prefix_kernel<<<dim3(1024), dim3(256), 0, stream>>>(cS, cz);
  chunk_out_kernel<<<dim3(NC, BH), dim3(256), 0, stream>>>(pqb, pkb, vb, cS, cz, attnb);
  gemm_out_kernel<<<dim3(N_ / 128, E_ / 64), dim3(256), 0, stream>>>(attnb, wob, bo, out);
}